// Round 4
// baseline (916.513 us; speedup 1.0000x reference)
//
#include <hip/hip_runtime.h>

typedef unsigned short ushort_t;
typedef __attribute__((ext_vector_type(8))) short short8;
typedef __attribute__((ext_vector_type(4))) float f32x4;

#define N_NODES 50000
#define DIM     128
#define NBASE   4
#define N_EDGE  320000
#define DM_BLOCKS 1024

// canonical fp32 small-tensor layout (element offsets)
#define C_COMP1 0
#define C_COMP2 100
#define C_BIAS1 200
#define C_BIAS2 328
#define C_REL   456
#define C_EBIAS 1992
#define C_TOTAL 2120

__device__ __forceinline__ float bf2f(ushort_t u) {
    union { unsigned int i; float f; } v; v.i = ((unsigned int)u) << 16; return v.f;
}
__device__ __forceinline__ ushort_t f2bf(float f) {
    union { float f; unsigned int i; } v; v.f = f;
    unsigned int u = v.i;
    u = (u + 0x7FFFu + ((u >> 16) & 1u)) >> 16;   // RNE
    return (ushort_t)u;
}
__device__ __forceinline__ float readf(const void* p, int i, int isbf) {
    return isbf ? bf2f(((const ushort_t*)p)[i]) : ((const float*)p)[i];
}
__device__ __forceinline__ float softplus(float x) {
    if (x > 20.f) return x;
    if (x < -20.f) return expf(x);
    return log1pf(expf(x));
}
// OCP e4m3fn encode (RNE, denormals, clamp at 448)
__device__ __forceinline__ unsigned char f2e4m3(float f) {
    union { float f; unsigned int u; } v; v.f = f;
    unsigned char s = (unsigned char)((v.u >> 24) & 0x80);
    float a = fabsf(f);
    if (a >= 448.f) return s | 0x7E;
    if (a < 0.015625f) {
        int q = (int)rintf(a * 512.0f);
        return s | (unsigned char)q;
    }
    unsigned int u = v.u & 0x7FFFFFFFu;
    u = u + 0x7FFFFu + ((u >> 20) & 1u);
    int exp = (int)(u >> 23) - 127;
    if (exp > 8) return s | 0x7E;
    unsigned int mant = (u >> 20) & 7u;
    return s | (unsigned char)(((exp + 7) << 3) | mant);
}
__device__ __forceinline__ float e4m32f(unsigned char c) {
    int e = (c >> 3) & 15, mm = c & 7;
    float a;
    if (e) { union { unsigned u; float f; } w;
             w.u = ((unsigned)(e + 120) << 23) | ((unsigned)mm << 20); a = w.f; }
    else a = (float)mm * 0.001953125f;
    return (c & 0x80) ? -a : a;
}

// Detect float dtype of entity_embedding: bf16 -> ~256/256 ushorts with exp field in [100,126]; fp32 -> ~141.
__global__ void k_detect(const ushort_t* __restrict__ emb, int* __restrict__ flag) {
    __shared__ int cnt;
    if (threadIdx.x == 0) cnt = 0;
    __syncthreads();
    int e = (emb[threadIdx.x] >> 7) & 0xFF;
    if (e >= 100 && e <= 126) atomicAdd(&cnt, 1);
    __syncthreads();
    if (threadIdx.x == 0) *flag = (cnt >= 200) ? 1 : 0;  // 1 = bf16 inputs
}

__global__ void k_small(const void* comp1, const void* comp2, const void* b1, const void* b2,
                        const void* rel, const void* eb, float* __restrict__ canon,
                        const int* __restrict__ flag) {
    int isbf = *flag;
    for (int i = threadIdx.x; i < C_TOTAL; i += blockDim.x) {
        float v;
        if      (i < C_COMP2) v = readf(comp1, i - C_COMP1, isbf);
        else if (i < C_BIAS1) v = readf(comp2, i - C_COMP2, isbf);
        else if (i < C_BIAS2) v = readf(b1,    i - C_BIAS1, isbf);
        else if (i < C_REL)   v = readf(b2,    i - C_BIAS2, isbf);
        else if (i < C_EBIAS) v = readf(rel,   i - C_REL,   isbf);
        else                  v = readf(eb,    i - C_EBIAS, isbf);
        canon[i] = v;
    }
}

// bases [B,128in,128out] -> BT[(b*128+out)][in]  bf16
__global__ void k_repack(const void* __restrict__ bases, ushort_t* __restrict__ bt,
                         const int* __restrict__ flag) {
    int isbf = *flag;
    int i = blockIdx.x * blockDim.x + threadIdx.x;
    if (i >= NBASE * 128 * 128) return;
    int b = i >> 14, rest = i & 16383, row = rest >> 7, o = rest & 127;
    bt[(((b << 7) + o) << 7) + row] = f2bf(readf(bases, i, isbf));
}

__global__ void k_deg(const int* __restrict__ ei, float* __restrict__ deg) {
    int e = blockIdx.x * blockDim.x + threadIdx.x;
    if (e >= N_EDGE) return;
    atomicAdd(&deg[ei[N_EDGE + e]], 1.0f);
}

// hb[M x W*128] = X[M x 128] @ BT^T, X generated inline from `mode`:
//  mode<0: layer1, resolve 0/1 from *dflag. 0: fp32 emb+ebias relu. 1: bf16 emb+ebias relu.
//  2: fp32 agg/deg + bias1, relu (layer2 fused). 3: bf16 passthrough.
__global__ void k_gemm(const void* __restrict__ src, const float* __restrict__ degp,
                       const float* __restrict__ canon, const ushort_t* __restrict__ bt,
                       void* __restrict__ hb, const int* __restrict__ dflag, int mode,
                       int W, float S, int isfp8) {
    if (mode < 0) mode = *dflag;
    int lane = threadIdx.x;
    int m0 = blockIdx.x * 16, n0 = blockIdx.y * 64;
    int r = lane & 15, q = lane >> 4;
    int m = m0 + r;
    int RS = W << 7;
    f32x4 acc[4] = {};
    #pragma unroll
    for (int ks = 0; ks < 4; ++ks) {
        int k0 = ks * 32 + q * 8;
        short8 a;
        if (mode == 3) {
            a = *(const short8*)((const ushort_t*)src + (size_t)m * 128 + k0);
        } else {
            float v[8];
            if (mode == 2) {
                float d = fmaxf(degp[m], 1.0f);
                const float* p = (const float*)src + (size_t)m * 128 + k0;
                #pragma unroll
                for (int j = 0; j < 8; ++j) v[j] = fmaxf(p[j] / d + canon[C_BIAS1 + k0 + j], 0.f);
            } else if (mode == 0) {
                const float* p = (const float*)src + (size_t)m * 128 + k0;
                #pragma unroll
                for (int j = 0; j < 8; ++j) v[j] = fmaxf(p[j] + canon[C_EBIAS + k0 + j], 0.f);
            } else {
                const ushort_t* p = (const ushort_t*)src + (size_t)m * 128 + k0;
                #pragma unroll
                for (int j = 0; j < 8; ++j) v[j] = fmaxf(bf2f(p[j]) + canon[C_EBIAS + k0 + j], 0.f);
            }
            #pragma unroll
            for (int j = 0; j < 8; ++j) ((short*)&a)[j] = (short)f2bf(v[j]);
        }
        #pragma unroll
        for (int t = 0; t < 4; ++t) {
            size_t brow = (size_t)(n0 + t * 16 + r) * 128;
            short8 b = *(const short8*)(bt + brow + k0);
            acc[t] = __builtin_amdgcn_mfma_f32_16x16x32_bf16(a, b, acc[t], 0, 0, 0);
        }
    }
    #pragma unroll
    for (int t = 0; t < 4; ++t) {
        int col = n0 + t * 16 + r;             // D: col=lane&15, row=quad*4+reg (m89-verified)
        int rbase = m0 + (q << 2);
        #pragma unroll
        for (int i = 0; i < 4; ++i) {
            if (isfp8) ((unsigned char*)hb)[(size_t)(rbase + i) * RS + col] = f2e4m3(acc[t][i] * S);
            else       ((ushort_t*)hb)[(size_t)(rbase + i) * RS + col] = f2bf(acc[t][i]);
        }
    }
}

// agg[dst,o] += sum_{b<W} comp[r, b0+b] * hb[src, b*128+o] * invS
__global__ void k_edge(const void* __restrict__ hb, const int* __restrict__ ei,
                       const int* __restrict__ et, const float* __restrict__ compf,
                       float* __restrict__ agg, int W, int b0, float invS, int isfp8) {
    int tid = threadIdx.x;                  // 256 -> 2 edges/block
    int e = blockIdx.x * 2 + (tid >> 7);
    int o = tid & 127;
    int src = ei[e], dst = ei[N_EDGE + e], r = et[e];
    int RS = W << 7;
    float m = 0.f;
    if (isfp8) {
        const unsigned char* hp = (const unsigned char*)hb + (size_t)src * RS;
        for (int b = 0; b < W; ++b)
            m += compf[r * 4 + b0 + b] * invS * e4m32f(hp[(b << 7) + o]);
    } else {
        const ushort_t* hp = (const ushort_t*)hb + (size_t)src * RS;
        for (int b = 0; b < W; ++b)
            m += compf[r * 4 + b0 + b] * bf2f(hp[(b << 7) + o]);
    }
    atomicAdd(&agg[(size_t)dst * 128 + o], m);
}

// x1 = bf16(relu(agg/deg + bias1))  (only used by the W=1 streaming config)
__global__ void k_xupd(const float* __restrict__ agg, const float* __restrict__ deg,
                       const float* __restrict__ canon, ushort_t* __restrict__ xbf) {
    int i = blockIdx.x * blockDim.x + threadIdx.x;
    if (i >= N_NODES * 128) return;
    float d = fmaxf(deg[i >> 7], 1.0f);
    xbf[i] = f2bf(fmaxf(agg[i] / d + canon[C_BIAS1 + (i & 127)], 0.f));
}

// DistMult + loss/auc partials; layer-2 normalize fused. FP32 OUTPUT.
__global__ void k_distmult(const float* __restrict__ agg, const float* __restrict__ deg,
                           const float* __restrict__ canon, const int* __restrict__ ei,
                           const int* __restrict__ et, const int* __restrict__ neg,
                           float* __restrict__ outp, float* __restrict__ partials) {
    const float* b2  = canon + C_BIAS2;
    const float* rel = canon + C_REL;
    int lane = threadIdx.x & 63;
    int w = blockIdx.x * (blockDim.x >> 6) + (threadIdx.x >> 6);
    int nw = DM_BLOCKS * (blockDim.x >> 6);
    float aL1 = 0.f, aL2 = 0.f, aA = 0.f;
    float bb0 = b2[lane], bb1 = b2[lane + 64];
    for (int e = w; e < N_EDGE; e += nw) {
        int h = ei[e], t = ei[N_EDGE + e], r = et[e], qn = neg[e];
        float dh = fmaxf(deg[h], 1.f), dt = fmaxf(deg[t], 1.f), dq = fmaxf(deg[qn], 1.f);
        const float* ah = agg + (size_t)h * 128;
        const float* at = agg + (size_t)t * 128;
        const float* aq = agg + (size_t)qn * 128;
        float xh0 = ah[lane] / dh + bb0, xh1 = ah[lane + 64] / dh + bb1;
        float xt0 = at[lane] / dt + bb0, xt1 = at[lane + 64] / dt + bb1;
        float xq0 = aq[lane] / dq + bb0, xq1 = aq[lane + 64] / dq + bb1;
        float rr0 = rel[r * 128 + lane], rr1 = rel[r * 128 + lane + 64];
        float a0 = xh0 * rr0, a1 = xh1 * rr1;
        float sp = a0 * xt0 + a1 * xt1;
        float sn = a0 * xq0 + a1 * xq1;
        #pragma unroll
        for (int off = 32; off; off >>= 1) {
            sp += __shfl_down(sp, off);
            sn += __shfl_down(sn, off);
        }
        if (lane == 0) {
            outp[e] = sp;                       // fp32 output
            aL1 += softplus(-sp);
            aL2 += softplus(sn);
            aA  += (sp > sn) ? 1.0f : 0.0f;
        }
    }
    __shared__ float s[3][8];
    int wl = threadIdx.x >> 6;
    if (lane == 0) { s[0][wl] = aL1; s[1][wl] = aL2; s[2][wl] = aA; }
    __syncthreads();
    if (threadIdx.x == 0) {
        int nwb = blockDim.x >> 6;
        float t0 = 0.f, t1 = 0.f, t2 = 0.f;
        for (int i = 0; i < nwb; ++i) { t0 += s[0][i]; t1 += s[1][i]; t2 += s[2][i]; }
        partials[blockIdx.x * 3 + 0] = t0;
        partials[blockIdx.x * 3 + 1] = t1;
        partials[blockIdx.x * 3 + 2] = t2;
    }
}

__global__ void k_final(const float* __restrict__ partials, float* __restrict__ outp) {
    __shared__ float s[3][256];
    int tid = threadIdx.x;
    float t0 = 0.f, t1 = 0.f, t2 = 0.f;
    for (int i = tid; i < DM_BLOCKS; i += 256) {
        t0 += partials[i * 3 + 0];
        t1 += partials[i * 3 + 1];
        t2 += partials[i * 3 + 2];
    }
    s[0][tid] = t0; s[1][tid] = t1; s[2][tid] = t2;
    __syncthreads();
    for (int st = 128; st; st >>= 1) {
        if (tid < st) {
            s[0][tid] += s[0][tid + st];
            s[1][tid] += s[1][tid + st];
            s[2][tid] += s[2][tid + st];
        }
        __syncthreads();
    }
    if (tid == 0) {
        float inv = 1.0f / (float)N_EDGE;
        outp[N_EDGE]     = 0.5f * (s[0][0] * inv + s[1][0] * inv);   // fp32 loss
        outp[N_EDGE + 1] = s[2][0] * inv;                             // fp32 auc
    }
}

extern "C" void kernel_launch(void* const* d_in, const int* in_sizes, int n_in,
                              void* d_out, int out_size, void* d_ws, size_t ws_size,
                              hipStream_t stream) {
    const void* emb    = d_in[0];
    const void* ebias  = d_in[1];
    const void* bases1 = d_in[2];
    const void* comp1  = d_in[3];
    const void* bias1  = d_in[4];
    const void* bases2 = d_in[5];
    const void* comp2  = d_in[6];
    const void* bias2  = d_in[7];
    const void* rel    = d_in[8];
    const int*  ei     = (const int*)d_in[9];
    const int*  et     = (const int*)d_in[10];
    const int*  neg    = (const int*)d_in[11];
    float*      outp   = (float*)d_out;            // fp32 per reference output dtype

    // ---- adaptive config: largest footprint that fits ws_size ----
    const size_t commonB = 483584;                       // flag+canon+deg+bt1+bt2+part
    const size_t aggB    = (size_t)N_NODES * 128 * 4;    // 25.6 MB
    const size_t needA   = commonB + aggB + (size_t)N_NODES * 512 * 2;   // 77.3 MB
    const size_t needB   = commonB + aggB + (size_t)N_NODES * 512 * 1;   // 51.7 MB
    int W, fp8, use_x;
    if      (ws_size >= needA) { W = 4; fp8 = 0; use_x = 0; }
    else if (ws_size >= needB) { W = 4; fp8 = 1; use_x = 0; }
    else                       { W = 1; fp8 = 1; use_x = 1; }
    const float S1 = 1024.f, S2 = 2048.f;
    float s1 = fp8 ? S1 : 1.f, s2 = fp8 ? S2 : 1.f;
    float i1 = fp8 ? (1.f / S1) : 1.f, i2 = fp8 ? (1.f / S2) : 1.f;

    char* ws = (char*)d_ws;
    size_t off = 0;
    auto alloc = [&](size_t bytes) { char* p = ws + off; off += (bytes + 255) & ~(size_t)255; return p; };
    int*      flag  = (int*)alloc(256);
    float*    canon = (float*)alloc((size_t)C_TOTAL * 4);
    float*    deg   = (float*)alloc((size_t)N_NODES * 4);
    ushort_t* bt1   = (ushort_t*)alloc((size_t)512 * 128 * 2);
    ushort_t* bt2   = (ushort_t*)alloc((size_t)512 * 128 * 2);
    float*    part  = (float*)alloc((size_t)DM_BLOCKS * 3 * 4);
    float*    agg   = (float*)alloc(aggB);
    void*     hb    = (void*)alloc((size_t)N_NODES * (W * 128) * (fp8 ? 1 : 2));
    ushort_t* x     = use_x ? (ushort_t*)alloc((size_t)N_NODES * 128 * 2) : nullptr;

    k_detect<<<1, 256, 0, stream>>>((const ushort_t*)emb, flag);
    k_small<<<1, 256, 0, stream>>>(comp1, comp2, bias1, bias2, rel, ebias, canon, flag);
    hipMemsetAsync(deg, 0, (size_t)N_NODES * 4, stream);
    k_deg<<<N_EDGE / 256, 256, 0, stream>>>(ei, deg);
    k_repack<<<NBASE * 128 * 128 / 256, 256, 0, stream>>>(bases1, bt1, flag);
    k_repack<<<NBASE * 128 * 128 / 256, 256, 0, stream>>>(bases2, bt2, flag);

    dim3 ggrid(N_NODES / 16, W * 2);
    if (W == 4) {
        k_gemm<<<ggrid, 64, 0, stream>>>(emb, deg, canon, bt1, hb, flag, -1, 4, s1, fp8);
        hipMemsetAsync(agg, 0, aggB, stream);
        k_edge<<<N_EDGE / 2, 256, 0, stream>>>(hb, ei, et, canon + C_COMP1, agg, 4, 0, i1, fp8);
        k_gemm<<<ggrid, 64, 0, stream>>>(agg, deg, canon, bt2, hb, flag, 2, 4, s2, fp8);
        hipMemsetAsync(agg, 0, aggB, stream);
        k_edge<<<N_EDGE / 2, 256, 0, stream>>>(hb, ei, et, canon + C_COMP2, agg, 4, 0, i2, fp8);
    } else {
        hipMemsetAsync(agg, 0, aggB, stream);
        for (int c = 0; c < 4; ++c) {
            k_gemm<<<ggrid, 64, 0, stream>>>(emb, deg, canon, bt1 + c * 16384, hb, flag, -1, 1, s1, fp8);
            k_edge<<<N_EDGE / 2, 256, 0, stream>>>(hb, ei, et, canon + C_COMP1, agg, 1, c, i1, fp8);
        }
        k_xupd<<<N_NODES * 128 / 256, 256, 0, stream>>>(agg, deg, canon, x);
        hipMemsetAsync(agg, 0, aggB, stream);
        for (int c = 0; c < 4; ++c) {
            k_gemm<<<ggrid, 64, 0, stream>>>(x, deg, canon, bt2 + c * 16384, hb, flag, 3, 1, s2, fp8);
            k_edge<<<N_EDGE / 2, 256, 0, stream>>>(hb, ei, et, canon + C_COMP2, agg, 1, c, i2, fp8);
        }
    }
    k_distmult<<<DM_BLOCKS, 256, 0, stream>>>(agg, deg, canon, ei, et, neg, outp, part);
    k_final<<<1, 256, 0, stream>>>(part, outp);
}

// Round 5
// 656.776 us; speedup vs baseline: 1.3955x; 1.3955x over previous
//
#include <hip/hip_runtime.h>

typedef unsigned short ushort_t;
typedef __attribute__((ext_vector_type(8))) short short8;
typedef __attribute__((ext_vector_type(4))) float f32x4;

#define N_NODES 50000
#define NBASE   4
#define N_EDGE  320000
#define DM_BLOCKS 1024
#define N_GROUPS (N_EDGE / 8)

// canonical fp32 small-tensor layout (element offsets)
#define C_COMP1 0
#define C_COMP2 100
#define C_BIAS1 200
#define C_BIAS2 328
#define C_REL   456
#define C_EBIAS 1992
#define C_TOTAL 2120

__device__ __forceinline__ float bf2f(ushort_t u) {
    union { unsigned int i; float f; } v; v.i = ((unsigned int)u) << 16; return v.f;
}
__device__ __forceinline__ ushort_t f2bf(float f) {
    union { float f; unsigned int i; } v; v.f = f;
    unsigned int u = v.i;
    u = (u + 0x7FFFu + ((u >> 16) & 1u)) >> 16;   // RNE
    return (ushort_t)u;
}
__device__ __forceinline__ float readf(const void* p, int i, int isbf) {
    return isbf ? bf2f(((const ushort_t*)p)[i]) : ((const float*)p)[i];
}
__device__ __forceinline__ float softplus(float x) {
    if (x > 20.f) return x;
    if (x < -20.f) return expf(x);
    return log1pf(expf(x));
}
// OCP e4m3fn encode (RNE, denormals, clamp at 448)
__device__ __forceinline__ unsigned char f2e4m3(float f) {
    union { float f; unsigned int u; } v; v.f = f;
    unsigned char s = (unsigned char)((v.u >> 24) & 0x80);
    float a = fabsf(f);
    if (a >= 448.f) return s | 0x7E;
    if (a < 0.015625f) {
        int q = (int)rintf(a * 512.0f);
        return s | (unsigned char)q;
    }
    unsigned int u = v.u & 0x7FFFFFFFu;
    u = u + 0x7FFFFu + ((u >> 20) & 1u);
    int exp = (int)(u >> 23) - 127;
    if (exp > 8) return s | 0x7E;
    unsigned int mant = (u >> 20) & 7u;
    return s | (unsigned char)(((exp + 7) << 3) | mant);
}
__device__ __forceinline__ float e4m32f(unsigned char c) {
    int e = (c >> 3) & 15, mm = c & 7;
    float a;
    if (e) { union { unsigned u; float f; } w;
             w.u = ((unsigned)(e + 120) << 23) | ((unsigned)mm << 20); a = w.f; }
    else a = (float)mm * 0.001953125f;
    return (c & 0x80) ? -a : a;
}

// Detect float dtype of entity_embedding (bf16 vs fp32) from bit patterns.
__global__ void k_detect(const ushort_t* __restrict__ emb, int* __restrict__ flag) {
    __shared__ int cnt;
    if (threadIdx.x == 0) cnt = 0;
    __syncthreads();
    int e = (emb[threadIdx.x] >> 7) & 0xFF;
    if (e >= 100 && e <= 126) atomicAdd(&cnt, 1);
    __syncthreads();
    if (threadIdx.x == 0) *flag = (cnt >= 200) ? 1 : 0;  // 1 = bf16 inputs
}

__global__ void k_small(const void* comp1, const void* comp2, const void* b1, const void* b2,
                        const void* rel, const void* eb, float* __restrict__ canon,
                        const int* __restrict__ flag) {
    int isbf = *flag;
    for (int i = threadIdx.x; i < C_TOTAL; i += blockDim.x) {
        float v;
        if      (i < C_COMP2) v = readf(comp1, i - C_COMP1, isbf);
        else if (i < C_BIAS1) v = readf(comp2, i - C_COMP2, isbf);
        else if (i < C_BIAS2) v = readf(b1,    i - C_BIAS1, isbf);
        else if (i < C_REL)   v = readf(b2,    i - C_BIAS2, isbf);
        else if (i < C_EBIAS) v = readf(rel,   i - C_REL,   isbf);
        else                  v = readf(eb,    i - C_EBIAS, isbf);
        canon[i] = v;
    }
}

// bases [B,128in,128out] -> BT[(b*128+out)][in]  bf16
__global__ void k_repack(const void* __restrict__ bases, ushort_t* __restrict__ bt,
                         const int* __restrict__ flag) {
    int isbf = *flag;
    int i = blockIdx.x * blockDim.x + threadIdx.x;
    if (i >= NBASE * 128 * 128) return;
    int b = i >> 14, rest = i & 16383, row = rest >> 7, o = rest & 127;
    bt[(((b << 7) + o) << 7) + row] = f2bf(readf(bases, i, isbf));
}

// ---------------- CSR build (dst-indexed) ----------------
__global__ void k_cnt(const int* __restrict__ ei, int* __restrict__ cnt) {
    int e = blockIdx.x * blockDim.x + threadIdx.x;
    if (e >= N_EDGE) return;
    atomicAdd(&cnt[ei[N_EDGE + e]], 1);
}

// exclusive scan of cnt[50000] -> ptr[50001], copy to cursor. single block, 1024 thr.
__global__ void k_scan(const int* __restrict__ cnt, int* __restrict__ ptr,
                       int* __restrict__ cursor) {
    __shared__ int part[1024];
    const int CH = 49;   // 1024*49 = 50176 >= 50000
    int t = threadIdx.x;
    int base = t * CH;
    int s = 0;
    for (int i = 0; i < CH; ++i) {
        int idx = base + i;
        if (idx < N_NODES) s += cnt[idx];
    }
    part[t] = s;
    __syncthreads();
    for (int off = 1; off < 1024; off <<= 1) {
        int v = (t >= off) ? part[t - off] : 0;
        __syncthreads();
        part[t] += v;
        __syncthreads();
    }
    int run = part[t] - s;   // exclusive offset of this chunk
    for (int i = 0; i < CH; ++i) {
        int idx = base + i;
        if (idx < N_NODES) { ptr[idx] = run; cursor[idx] = run; run += cnt[idx]; }
    }
    if (t == 1023) ptr[N_NODES] = run;
}

__global__ void k_fill(const int* __restrict__ ei, const int* __restrict__ et,
                       int* __restrict__ cursor, unsigned int* __restrict__ packed) {
    int e = blockIdx.x * blockDim.x + threadIdx.x;
    if (e >= N_EDGE) return;
    int dst = ei[N_EDGE + e];
    int pos = atomicAdd(&cursor[dst], 1);
    packed[pos] = (unsigned int)(ei[e] & 0xFFFF) | ((unsigned int)et[e] << 16);
}

// ---------------- GEMM hb = X @ BT^T ----------------
//  mode<0: resolve 0/1 from *dflag. 0: fp32 emb+ebias relu. 1: bf16 emb+ebias relu.
//  2: fp32 agg/cnt + bias1, relu (layer2 fused). 3: bf16 passthrough.
__global__ void k_gemm(const void* __restrict__ src, const int* __restrict__ cntp,
                       const float* __restrict__ canon, const ushort_t* __restrict__ bt,
                       void* __restrict__ hb, const int* __restrict__ dflag, int mode,
                       int W, float S, int isfp8) {
    if (mode < 0) mode = *dflag;
    int lane = threadIdx.x;
    int m0 = blockIdx.x * 16, n0 = blockIdx.y * 64;
    int r = lane & 15, q = lane >> 4;
    int m = m0 + r;
    int RS = W << 7;
    f32x4 acc[4] = {};
    #pragma unroll
    for (int ks = 0; ks < 4; ++ks) {
        int k0 = ks * 32 + q * 8;
        short8 a;
        if (mode == 3) {
            a = *(const short8*)((const ushort_t*)src + (size_t)m * 128 + k0);
        } else {
            float v[8];
            if (mode == 2) {
                float d = fmaxf((float)cntp[m], 1.0f);
                const float* p = (const float*)src + (size_t)m * 128 + k0;
                #pragma unroll
                for (int j = 0; j < 8; ++j) v[j] = fmaxf(p[j] / d + canon[C_BIAS1 + k0 + j], 0.f);
            } else if (mode == 0) {
                const float* p = (const float*)src + (size_t)m * 128 + k0;
                #pragma unroll
                for (int j = 0; j < 8; ++j) v[j] = fmaxf(p[j] + canon[C_EBIAS + k0 + j], 0.f);
            } else {
                const ushort_t* p = (const ushort_t*)src + (size_t)m * 128 + k0;
                #pragma unroll
                for (int j = 0; j < 8; ++j) v[j] = fmaxf(bf2f(p[j]) + canon[C_EBIAS + k0 + j], 0.f);
            }
            #pragma unroll
            for (int j = 0; j < 8; ++j) ((short*)&a)[j] = (short)f2bf(v[j]);
        }
        #pragma unroll
        for (int t = 0; t < 4; ++t) {
            size_t brow = (size_t)(n0 + t * 16 + r) * 128;
            short8 b = *(const short8*)(bt + brow + k0);
            acc[t] = __builtin_amdgcn_mfma_f32_16x16x32_bf16(a, b, acc[t], 0, 0, 0);
        }
    }
    #pragma unroll
    for (int t = 0; t < 4; ++t) {
        int col = n0 + t * 16 + r;             // D: col=lane&15, row=quad*4+reg (m89-verified)
        int rbase = m0 + (q << 2);
        #pragma unroll
        for (int i = 0; i < 4; ++i) {
            if (isfp8) ((unsigned char*)hb)[(size_t)(rbase + i) * RS + col] = f2e4m3(acc[t][i] * S);
            else       ((ushort_t*)hb)[(size_t)(rbase + i) * RS + col] = f2bf(acc[t][i]);
        }
    }
}

// ---------------- CSR gather-aggregate (replaces atomic scatter) ----------------
// agg[m,o] = invS * sum_{e in CSR[m]} sum_b comp[r_e,b] * hb[src_e, b*128+o]
__global__ void k_agg(const void* __restrict__ hb, const int* __restrict__ ptr,
                      const unsigned int* __restrict__ packed, const float* __restrict__ compf,
                      float* __restrict__ agg, float invS, int isfp8) {
    int tid = threadIdx.x;                  // 256 -> 2 nodes/block
    int m = blockIdx.x * 2 + (tid >> 7);
    int o = tid & 127;
    int beg = ptr[m], end = ptr[m + 1];
    float acc = 0.f;
    for (int i = beg; i < end; ++i) {
        unsigned int p = packed[i];
        int src = (int)(p & 0xFFFFu);
        const float* cp = compf + (p >> 16) * 4;
        if (isfp8) {
            const unsigned char* hp = (const unsigned char*)hb + (size_t)src * 512;
            acc += cp[0] * e4m32f(hp[o])       + cp[1] * e4m32f(hp[128 + o])
                 + cp[2] * e4m32f(hp[256 + o]) + cp[3] * e4m32f(hp[384 + o]);
        } else {
            const ushort_t* hp = (const ushort_t*)hb + (size_t)src * 512;
            acc += cp[0] * bf2f(hp[o])       + cp[1] * bf2f(hp[128 + o])
                 + cp[2] * bf2f(hp[256 + o]) + cp[3] * bf2f(hp[384 + o]);
        }
    }
    agg[(size_t)m * 128 + o] = acc * invS;
}

// x2 = agg/max(cnt,1) + bias2, in place
__global__ void k_x2(float* __restrict__ agg, const int* __restrict__ cnt,
                     const float* __restrict__ canon) {
    int i = blockIdx.x * blockDim.x + threadIdx.x;
    if (i >= N_NODES * 128) return;
    float d = fmaxf((float)cnt[i >> 7], 1.0f);
    agg[i] = agg[i] / d + canon[C_BIAS2 + (i & 127)];
}

// ---------------- DistMult: 8 lanes/edge, 8 edges/wave ----------------
__global__ void k_distmult8(const float* __restrict__ x2, const float* __restrict__ canon,
                            const int* __restrict__ ei, const int* __restrict__ et,
                            const int* __restrict__ neg, float* __restrict__ outp,
                            float* __restrict__ partials) {
    const float* rel = canon + C_REL;
    int lane = threadIdx.x & 63;
    int g = lane >> 3;                 // edge slot within wave (0..7)
    int l = lane & 7;                  // element group (16 elems each)
    int w = (blockIdx.x * blockDim.x + threadIdx.x) >> 6;   // global wave id
    int nw = (DM_BLOCKS * 256) >> 6;
    float aL1 = 0.f, aL2 = 0.f, aA = 0.f;
    for (int gid = w; gid < N_GROUPS; gid += nw) {
        int e = gid * 8 + g;
        int h = ei[e], t = ei[N_EDGE + e], r = et[e], qn = neg[e];
        const f32x4* xh = (const f32x4*)(x2 + (size_t)h * 128 + l * 16);
        const f32x4* xt = (const f32x4*)(x2 + (size_t)t * 128 + l * 16);
        const f32x4* xq = (const f32x4*)(x2 + (size_t)qn * 128 + l * 16);
        const f32x4* rr = (const f32x4*)(rel + r * 128 + l * 16);
        float sp = 0.f, sn = 0.f;
        #pragma unroll
        for (int j = 0; j < 4; ++j) {
            f32x4 a = xh[j] * rr[j];
            f32x4 vp = a * xt[j];
            f32x4 vn = a * xq[j];
            sp += vp.x + vp.y + vp.z + vp.w;
            sn += vn.x + vn.y + vn.z + vn.w;
        }
        sp += __shfl_down(sp, 4); sn += __shfl_down(sn, 4);
        sp += __shfl_down(sp, 2); sn += __shfl_down(sn, 2);
        sp += __shfl_down(sp, 1); sn += __shfl_down(sn, 1);
        if (l == 0) {                   // lanes 0,8,..,56: one pass handles 8 edges
            outp[e] = sp;
            aL1 += softplus(-sp);
            aL2 += softplus(sn);
            aA  += (sp > sn) ? 1.0f : 0.0f;
        }
    }
    // wave reduce (non-l0 lanes carry 0)
    #pragma unroll
    for (int off = 32; off; off >>= 1) {
        aL1 += __shfl_down(aL1, off);
        aL2 += __shfl_down(aL2, off);
        aA  += __shfl_down(aA,  off);
    }
    __shared__ float s[3][4];
    int wl = threadIdx.x >> 6;
    if (lane == 0) { s[0][wl] = aL1; s[1][wl] = aL2; s[2][wl] = aA; }
    __syncthreads();
    if (threadIdx.x == 0) {
        float t0 = 0.f, t1 = 0.f, t2 = 0.f;
        for (int i = 0; i < 4; ++i) { t0 += s[0][i]; t1 += s[1][i]; t2 += s[2][i]; }
        partials[blockIdx.x * 3 + 0] = t0;
        partials[blockIdx.x * 3 + 1] = t1;
        partials[blockIdx.x * 3 + 2] = t2;
    }
}

__global__ void k_final(const float* __restrict__ partials, float* __restrict__ outp) {
    __shared__ float s[3][256];
    int tid = threadIdx.x;
    float t0 = 0.f, t1 = 0.f, t2 = 0.f;
    for (int i = tid; i < DM_BLOCKS; i += 256) {
        t0 += partials[i * 3 + 0];
        t1 += partials[i * 3 + 1];
        t2 += partials[i * 3 + 2];
    }
    s[0][tid] = t0; s[1][tid] = t1; s[2][tid] = t2;
    __syncthreads();
    for (int st = 128; st; st >>= 1) {
        if (tid < st) {
            s[0][tid] += s[0][tid + st];
            s[1][tid] += s[1][tid + st];
            s[2][tid] += s[2][tid + st];
        }
        __syncthreads();
    }
    if (tid == 0) {
        float inv = 1.0f / (float)N_EDGE;
        outp[N_EDGE]     = 0.5f * (s[0][0] * inv + s[1][0] * inv);
        outp[N_EDGE + 1] = s[2][0] * inv;
    }
}

// atomic-scatter fallback (W=1 streaming config only)
__global__ void k_edge(const void* __restrict__ hb, const int* __restrict__ ei,
                       const int* __restrict__ et, const float* __restrict__ compf,
                       float* __restrict__ agg, int b0, float invS) {
    int tid = threadIdx.x;
    int e = blockIdx.x * 2 + (tid >> 7);
    int o = tid & 127;
    int src = ei[e], dst = ei[N_EDGE + e], r = et[e];
    const unsigned char* hp = (const unsigned char*)hb + (size_t)src * 128;
    float m = compf[r * 4 + b0] * invS * e4m32f(hp[o]);
    atomicAdd(&agg[(size_t)dst * 128 + o], m);
}
__global__ void k_xupd(const float* __restrict__ agg, const int* __restrict__ cnt,
                       const float* __restrict__ canon, ushort_t* __restrict__ xbf) {
    int i = blockIdx.x * blockDim.x + threadIdx.x;
    if (i >= N_NODES * 128) return;
    float d = fmaxf((float)cnt[i >> 7], 1.0f);
    xbf[i] = f2bf(fmaxf(agg[i] / d + canon[C_BIAS1 + (i & 127)], 0.f));
}

extern "C" void kernel_launch(void* const* d_in, const int* in_sizes, int n_in,
                              void* d_out, int out_size, void* d_ws, size_t ws_size,
                              hipStream_t stream) {
    const void* emb    = d_in[0];
    const void* ebias  = d_in[1];
    const void* bases1 = d_in[2];
    const void* comp1  = d_in[3];
    const void* bias1  = d_in[4];
    const void* bases2 = d_in[5];
    const void* comp2  = d_in[6];
    const void* bias2  = d_in[7];
    const void* rel    = d_in[8];
    const int*  ei     = (const int*)d_in[9];
    const int*  et     = (const int*)d_in[10];
    const int*  neg    = (const int*)d_in[11];
    float*      outp   = (float*)d_out;

    // ---- adaptive config ----
    const size_t commonB = 256 + 8704 + 3 * 200192 + 2 * 131072 + 12288 + 1280000 + 256;
    const size_t aggB    = (size_t)N_NODES * 128 * 4;                       // 25.6 MB
    const size_t needA   = commonB + aggB + (size_t)N_NODES * 512 * 2;      // ~78.9 MB  bf16 hb
    const size_t needB   = commonB + aggB + (size_t)N_NODES * 512 * 1;      // ~53.3 MB  fp8 hb
    int fp8, streamC;
    if      (ws_size >= needA) { fp8 = 0; streamC = 0; }
    else if (ws_size >= needB) { fp8 = 1; streamC = 0; }
    else                       { fp8 = 1; streamC = 1; }
    const float S1 = 1024.f, S2 = 2048.f;
    float s1 = fp8 ? S1 : 1.f, s2 = fp8 ? S2 : 1.f;
    float i1 = fp8 ? (1.f / S1) : 1.f, i2 = fp8 ? (1.f / S2) : 1.f;

    char* ws = (char*)d_ws;
    size_t off = 0;
    auto alloc = [&](size_t bytes) { char* p = ws + off; off += (bytes + 255) & ~(size_t)255; return p; };
    int*          flag   = (int*)alloc(256);
    float*        canon  = (float*)alloc((size_t)C_TOTAL * 4);
    int*          cnt    = (int*)alloc((size_t)N_NODES * 4);
    int*          ptr    = (int*)alloc((size_t)(N_NODES + 1) * 4);
    int*          cursor = (int*)alloc((size_t)N_NODES * 4);
    ushort_t*     bt1    = (ushort_t*)alloc((size_t)512 * 128 * 2);
    ushort_t*     bt2    = (ushort_t*)alloc((size_t)512 * 128 * 2);
    float*        part   = (float*)alloc((size_t)DM_BLOCKS * 3 * 4);
    unsigned int* packed = (unsigned int*)alloc((size_t)N_EDGE * 4);
    float*        agg    = (float*)alloc(aggB);
    void*         hb     = (void*)alloc((size_t)N_NODES * 512 * (fp8 ? 1 : 2) / (streamC ? 4 : 1));
    ushort_t*     x      = streamC ? (ushort_t*)alloc((size_t)N_NODES * 128 * 2) : nullptr;

    k_detect<<<1, 256, 0, stream>>>((const ushort_t*)emb, flag);
    k_small<<<1, 256, 0, stream>>>(comp1, comp2, bias1, bias2, rel, ebias, canon, flag);
    hipMemsetAsync(cnt, 0, (size_t)N_NODES * 4, stream);
    k_cnt<<<N_EDGE / 256, 256, 0, stream>>>(ei, cnt);
    k_scan<<<1, 1024, 0, stream>>>(cnt, ptr, cursor);
    k_fill<<<N_EDGE / 256, 256, 0, stream>>>(ei, et, cursor, packed);
    k_repack<<<NBASE * 128 * 128 / 256, 256, 0, stream>>>(bases1, bt1, flag);
    k_repack<<<NBASE * 128 * 128 / 256, 256, 0, stream>>>(bases2, bt2, flag);

    if (!streamC) {
        dim3 ggrid(N_NODES / 16, 8);
        // layer 1
        k_gemm<<<ggrid, 64, 0, stream>>>(emb, cnt, canon, bt1, hb, flag, -1, 4, s1, fp8);
        k_agg<<<N_NODES / 2, 256, 0, stream>>>(hb, ptr, packed, canon + C_COMP1, agg, i1, fp8);
        // layer 2 (gemm mode 2 reads raw agg + cnt + bias1 inline)
        k_gemm<<<ggrid, 64, 0, stream>>>(agg, cnt, canon, bt2, hb, flag, 2, 4, s2, fp8);
        k_agg<<<N_NODES / 2, 256, 0, stream>>>(hb, ptr, packed, canon + C_COMP2, agg, i2, fp8);
    } else {
        dim3 ggrid(N_NODES / 16, 2);
        hipMemsetAsync(agg, 0, aggB, stream);
        for (int c = 0; c < 4; ++c) {
            k_gemm<<<ggrid, 64, 0, stream>>>(emb, cnt, canon, bt1 + c * 16384, hb, flag, -1, 1, s1, 1);
            k_edge<<<N_EDGE / 2, 256, 0, stream>>>(hb, ei, et, canon + C_COMP1, agg, c, i1);
        }
        k_xupd<<<N_NODES * 128 / 256, 256, 0, stream>>>(agg, cnt, canon, x);
        hipMemsetAsync(agg, 0, aggB, stream);
        for (int c = 0; c < 4; ++c) {
            k_gemm<<<ggrid, 64, 0, stream>>>(x, cnt, canon, bt2 + c * 16384, hb, flag, 3, 1, s2, 1);
            k_edge<<<N_EDGE / 2, 256, 0, stream>>>(hb, ei, et, canon + C_COMP2, agg, c, i2);
        }
    }
    k_x2<<<N_NODES * 128 / 256, 256, 0, stream>>>(agg, cnt, canon);
    k_distmult8<<<DM_BLOCKS, 256, 0, stream>>>(agg, canon, ei, et, neg, outp, part);
    k_final<<<1, 256, 0, stream>>>(part, outp);
}

// Round 6
// 536.396 us; speedup vs baseline: 1.7086x; 1.2244x over previous
//
#include <hip/hip_runtime.h>

typedef unsigned short ushort_t;
typedef __attribute__((ext_vector_type(8))) short short8;
typedef __attribute__((ext_vector_type(4))) float f32x4;

#define N_NODES 50000
#define NBASE   4
#define N_EDGE  320000
#define DM_BLOCKS 1024
#define N_GROUPS (N_EDGE / 8)
#define SCAN_BLOCKS 49          // 49*1024 = 50176 >= 50000

// canonical fp32 small-tensor layout (element offsets)
#define C_COMP1 0
#define C_COMP2 100
#define C_BIAS1 200
#define C_BIAS2 328
#define C_REL   456
#define C_EBIAS 1992
#define C_TOTAL 2120

__device__ __forceinline__ float bf2f(ushort_t u) {
    union { unsigned int i; float f; } v; v.i = ((unsigned int)u) << 16; return v.f;
}
__device__ __forceinline__ ushort_t f2bf(float f) {
    union { float f; unsigned int i; } v; v.f = f;
    unsigned int u = v.i;
    u = (u + 0x7FFFu + ((u >> 16) & 1u)) >> 16;   // RNE
    return (ushort_t)u;
}
__device__ __forceinline__ float readf(const void* p, int i, int isbf) {
    return isbf ? bf2f(((const ushort_t*)p)[i]) : ((const float*)p)[i];
}
__device__ __forceinline__ float softplus(float x) {
    if (x > 20.f) return x;
    if (x < -20.f) return expf(x);
    return log1pf(expf(x));
}
// OCP e4m3fn encode (RNE, denormals, clamp at 448)
__device__ __forceinline__ unsigned char f2e4m3(float f) {
    union { float f; unsigned int u; } v; v.f = f;
    unsigned char s = (unsigned char)((v.u >> 24) & 0x80);
    float a = fabsf(f);
    if (a >= 448.f) return s | 0x7E;
    if (a < 0.015625f) {
        int q = (int)rintf(a * 512.0f);
        return s | (unsigned char)q;
    }
    unsigned int u = v.u & 0x7FFFFFFFu;
    u = u + 0x7FFFFu + ((u >> 20) & 1u);
    int exp = (int)(u >> 23) - 127;
    if (exp > 8) return s | 0x7E;
    unsigned int mant = (u >> 20) & 7u;
    return s | (unsigned char)(((exp + 7) << 3) | mant);
}
__device__ __forceinline__ float e4m32f(unsigned char c) {
    int e = (c >> 3) & 15, mm = c & 7;
    float a;
    if (e) { union { unsigned u; float f; } w;
             w.u = ((unsigned)(e + 120) << 23) | ((unsigned)mm << 20); a = w.f; }
    else a = (float)mm * 0.001953125f;
    return (c & 0x80) ? -a : a;
}

// Detect float dtype of entity_embedding (bf16 vs fp32) from bit patterns.
__global__ void k_detect(const ushort_t* __restrict__ emb, int* __restrict__ flag) {
    __shared__ int cnt;
    if (threadIdx.x == 0) cnt = 0;
    __syncthreads();
    int e = (emb[threadIdx.x] >> 7) & 0xFF;
    if (e >= 100 && e <= 126) atomicAdd(&cnt, 1);
    __syncthreads();
    if (threadIdx.x == 0) *flag = (cnt >= 200) ? 1 : 0;  // 1 = bf16 inputs
}

__global__ void k_small(const void* comp1, const void* comp2, const void* b1, const void* b2,
                        const void* rel, const void* eb, float* __restrict__ canon,
                        const int* __restrict__ flag) {
    int isbf = *flag;
    for (int i = threadIdx.x; i < C_TOTAL; i += blockDim.x) {
        float v;
        if      (i < C_COMP2) v = readf(comp1, i - C_COMP1, isbf);
        else if (i < C_BIAS1) v = readf(comp2, i - C_COMP2, isbf);
        else if (i < C_BIAS2) v = readf(b1,    i - C_BIAS1, isbf);
        else if (i < C_REL)   v = readf(b2,    i - C_BIAS2, isbf);
        else if (i < C_EBIAS) v = readf(rel,   i - C_REL,   isbf);
        else                  v = readf(eb,    i - C_EBIAS, isbf);
        canon[i] = v;
    }
}

// bases [B,128in,128out] -> BT[(b*128+out)][in]  bf16
__global__ void k_repack(const void* __restrict__ bases, ushort_t* __restrict__ bt,
                         const int* __restrict__ flag) {
    int isbf = *flag;
    int i = blockIdx.x * blockDim.x + threadIdx.x;
    if (i >= NBASE * 128 * 128) return;
    int b = i >> 14, rest = i & 16383, row = rest >> 7, o = rest & 127;
    bt[(((b << 7) + o) << 7) + row] = f2bf(readf(bases, i, isbf));
}

// ---------------- CSR build (dst-indexed) ----------------
__global__ void k_cnt(const int* __restrict__ ei, int* __restrict__ cnt) {
    int e = blockIdx.x * blockDim.x + threadIdx.x;
    if (e >= N_EDGE) return;
    atomicAdd(&cnt[ei[N_EDGE + e]], 1);
}

// scan stage 1: per-block LDS scan (1024 elems/block), local-exclusive -> ptr, block total -> bsum
__global__ void k_scan1(const int* __restrict__ cnt, int* __restrict__ ptr,
                        int* __restrict__ bsum) {
    __shared__ int s[1024];
    int t = threadIdx.x;
    int i = blockIdx.x * 1024 + t;
    int v = (i < N_NODES) ? cnt[i] : 0;
    s[t] = v;
    __syncthreads();
    for (int off = 1; off < 1024; off <<= 1) {
        int u = (t >= off) ? s[t - off] : 0;
        __syncthreads();
        s[t] += u;
        __syncthreads();
    }
    if (i < N_NODES) ptr[i] = s[t] - v;         // local exclusive
    if (t == 1023) bsum[blockIdx.x] = s[1023];
}

// scan stage 2: one wave scans the 49 block sums -> exclusive offsets
__global__ void k_scan2(const int* __restrict__ bsum, int* __restrict__ boff) {
    int t = threadIdx.x;                        // 64
    int v = (t < SCAN_BLOCKS) ? bsum[t] : 0;
    int orig = v;
    #pragma unroll
    for (int off = 1; off < 64; off <<= 1) {
        int u = __shfl_up(v, off);
        if (t >= off) v += u;
    }
    boff[t] = v - orig;                          // exclusive
}

// scan stage 3: add block offsets, write final ptr + cursor
__global__ void k_scan3(int* __restrict__ ptr, int* __restrict__ cursor,
                        const int* __restrict__ boff) {
    int t = threadIdx.x;
    int i = blockIdx.x * 1024 + t;
    if (i < N_NODES) {
        int p = ptr[i] + boff[blockIdx.x];
        ptr[i] = p;
        cursor[i] = p;
    }
    if (blockIdx.x == 0 && t == 0) ptr[N_NODES] = N_EDGE;   // total is exact by construction
}

__global__ void k_fill(const int* __restrict__ ei, const int* __restrict__ et,
                       int* __restrict__ cursor, unsigned int* __restrict__ packed) {
    int e = blockIdx.x * blockDim.x + threadIdx.x;
    if (e >= N_EDGE) return;
    int dst = ei[N_EDGE + e];
    int pos = atomicAdd(&cursor[dst], 1);
    packed[pos] = (unsigned int)(ei[e] & 0xFFFF) | ((unsigned int)et[e] << 16);
}

// ---------------- GEMM hb = X @ BT^T ----------------
//  mode<0: resolve 0/1 from *dflag. 0: fp32 emb+ebias relu. 1: bf16 emb+ebias relu.
//  2: fp32 agg/cnt + bias1, relu (layer2 fused). 3: bf16 passthrough.
__global__ void k_gemm(const void* __restrict__ src, const int* __restrict__ cntp,
                       const float* __restrict__ canon, const ushort_t* __restrict__ bt,
                       void* __restrict__ hb, const int* __restrict__ dflag, int mode,
                       int W, float S, int isfp8) {
    if (mode < 0) mode = *dflag;
    int lane = threadIdx.x;
    int m0 = blockIdx.x * 16, n0 = blockIdx.y * 64;
    int r = lane & 15, q = lane >> 4;
    int m = m0 + r;
    int RS = W << 7;
    f32x4 acc[4] = {};
    #pragma unroll
    for (int ks = 0; ks < 4; ++ks) {
        int k0 = ks * 32 + q * 8;
        short8 a;
        if (mode == 3) {
            a = *(const short8*)((const ushort_t*)src + (size_t)m * 128 + k0);
        } else {
            float v[8];
            if (mode == 2) {
                float d = fmaxf((float)cntp[m], 1.0f);
                const float* p = (const float*)src + (size_t)m * 128 + k0;
                #pragma unroll
                for (int j = 0; j < 8; ++j) v[j] = fmaxf(p[j] / d + canon[C_BIAS1 + k0 + j], 0.f);
            } else if (mode == 0) {
                const float* p = (const float*)src + (size_t)m * 128 + k0;
                #pragma unroll
                for (int j = 0; j < 8; ++j) v[j] = fmaxf(p[j] + canon[C_EBIAS + k0 + j], 0.f);
            } else {
                const ushort_t* p = (const ushort_t*)src + (size_t)m * 128 + k0;
                #pragma unroll
                for (int j = 0; j < 8; ++j) v[j] = fmaxf(bf2f(p[j]) + canon[C_EBIAS + k0 + j], 0.f);
            }
            #pragma unroll
            for (int j = 0; j < 8; ++j) ((short*)&a)[j] = (short)f2bf(v[j]);
        }
        #pragma unroll
        for (int t = 0; t < 4; ++t) {
            size_t brow = (size_t)(n0 + t * 16 + r) * 128;
            short8 b = *(const short8*)(bt + brow + k0);
            acc[t] = __builtin_amdgcn_mfma_f32_16x16x32_bf16(a, b, acc[t], 0, 0, 0);
        }
    }
    #pragma unroll
    for (int t = 0; t < 4; ++t) {
        int col = n0 + t * 16 + r;             // D: col=lane&15, row=quad*4+reg (m89-verified)
        int rbase = m0 + (q << 2);
        #pragma unroll
        for (int i = 0; i < 4; ++i) {
            if (isfp8) ((unsigned char*)hb)[(size_t)(rbase + i) * RS + col] = f2e4m3(acc[t][i] * S);
            else       ((ushort_t*)hb)[(size_t)(rbase + i) * RS + col] = f2bf(acc[t][i]);
        }
    }
}

// ---------------- CSR gather-aggregate ----------------
// acc = invS * sum_{e in CSR[m]} sum_b comp[r_e,b] * hb[src_e, b*128+o]
// omode 0: out = acc (raw fp32, layer 1 -> gemm mode 2)
// omode 1: out = acc/max(cnt,1) + bias2 (fp32 x2, layer 2; k_x2 fused away)
__global__ void k_agg(const void* __restrict__ hb, const int* __restrict__ ptr,
                      const unsigned int* __restrict__ packed, const float* __restrict__ compf,
                      const int* __restrict__ cnt, const float* __restrict__ canon,
                      float* __restrict__ out, float invS, int isfp8, int omode) {
    int tid = threadIdx.x;                  // 256 -> 2 nodes/block
    int m = blockIdx.x * 2 + (tid >> 7);
    int o = tid & 127;
    int beg = ptr[m], end = ptr[m + 1];
    float acc = 0.f;
    for (int i = beg; i < end; ++i) {
        unsigned int p = packed[i];
        int src = (int)(p & 0xFFFFu);
        const float* cp = compf + (p >> 16) * 4;
        if (isfp8) {
            const unsigned char* hp = (const unsigned char*)hb + (size_t)src * 512;
            acc += cp[0] * e4m32f(hp[o])       + cp[1] * e4m32f(hp[128 + o])
                 + cp[2] * e4m32f(hp[256 + o]) + cp[3] * e4m32f(hp[384 + o]);
        } else {
            const ushort_t* hp = (const ushort_t*)hb + (size_t)src * 512;
            acc += cp[0] * bf2f(hp[o])       + cp[1] * bf2f(hp[128 + o])
                 + cp[2] * bf2f(hp[256 + o]) + cp[3] * bf2f(hp[384 + o]);
        }
    }
    acc *= invS;
    if (omode == 1)
        acc = acc / fmaxf((float)cnt[m], 1.0f) + canon[C_BIAS2 + o];
    out[(size_t)m * 128 + o] = acc;
}

// ---------------- DistMult: 8 lanes/edge, 8 edges/wave ----------------
__global__ void k_distmult8(const float* __restrict__ x2, const float* __restrict__ canon,
                            const int* __restrict__ ei, const int* __restrict__ et,
                            const int* __restrict__ neg, float* __restrict__ outp,
                            float* __restrict__ partials) {
    const float* rel = canon + C_REL;
    int lane = threadIdx.x & 63;
    int g = lane >> 3;                 // edge slot within wave (0..7)
    int l = lane & 7;                  // element group (16 elems each)
    int w = (blockIdx.x * blockDim.x + threadIdx.x) >> 6;   // global wave id
    int nw = (DM_BLOCKS * 256) >> 6;
    float aL1 = 0.f, aL2 = 0.f, aA = 0.f;
    for (int gid = w; gid < N_GROUPS; gid += nw) {
        int e = gid * 8 + g;
        int h = ei[e], t = ei[N_EDGE + e], r = et[e], qn = neg[e];
        const f32x4* xh = (const f32x4*)(x2 + (size_t)h * 128 + l * 16);
        const f32x4* xt = (const f32x4*)(x2 + (size_t)t * 128 + l * 16);
        const f32x4* xq = (const f32x4*)(x2 + (size_t)qn * 128 + l * 16);
        const f32x4* rr = (const f32x4*)(rel + r * 128 + l * 16);
        float sp = 0.f, sn = 0.f;
        #pragma unroll
        for (int j = 0; j < 4; ++j) {
            f32x4 a = xh[j] * rr[j];
            f32x4 vp = a * xt[j];
            f32x4 vn = a * xq[j];
            sp += vp.x + vp.y + vp.z + vp.w;
            sn += vn.x + vn.y + vn.z + vn.w;
        }
        sp += __shfl_down(sp, 4); sn += __shfl_down(sn, 4);
        sp += __shfl_down(sp, 2); sn += __shfl_down(sn, 2);
        sp += __shfl_down(sp, 1); sn += __shfl_down(sn, 1);
        if (l == 0) {                   // lanes 0,8,..,56: one pass handles 8 edges
            outp[e] = sp;
            aL1 += softplus(-sp);
            aL2 += softplus(sn);
            aA  += (sp > sn) ? 1.0f : 0.0f;
        }
    }
    #pragma unroll
    for (int off = 32; off; off >>= 1) {
        aL1 += __shfl_down(aL1, off);
        aL2 += __shfl_down(aL2, off);
        aA  += __shfl_down(aA,  off);
    }
    __shared__ float s[3][4];
    int wl = threadIdx.x >> 6;
    if (lane == 0) { s[0][wl] = aL1; s[1][wl] = aL2; s[2][wl] = aA; }
    __syncthreads();
    if (threadIdx.x == 0) {
        float t0 = 0.f, t1 = 0.f, t2 = 0.f;
        for (int i = 0; i < 4; ++i) { t0 += s[0][i]; t1 += s[1][i]; t2 += s[2][i]; }
        partials[blockIdx.x * 3 + 0] = t0;
        partials[blockIdx.x * 3 + 1] = t1;
        partials[blockIdx.x * 3 + 2] = t2;
    }
}

__global__ void k_final(const float* __restrict__ partials, float* __restrict__ outp) {
    __shared__ float s[3][256];
    int tid = threadIdx.x;
    float t0 = 0.f, t1 = 0.f, t2 = 0.f;
    for (int i = tid; i < DM_BLOCKS; i += 256) {
        t0 += partials[i * 3 + 0];
        t1 += partials[i * 3 + 1];
        t2 += partials[i * 3 + 2];
    }
    s[0][tid] = t0; s[1][tid] = t1; s[2][tid] = t2;
    __syncthreads();
    for (int st = 128; st; st >>= 1) {
        if (tid < st) {
            s[0][tid] += s[0][tid + st];
            s[1][tid] += s[1][tid + st];
            s[2][tid] += s[2][tid + st];
        }
        __syncthreads();
    }
    if (tid == 0) {
        float inv = 1.0f / (float)N_EDGE;
        outp[N_EDGE]     = 0.5f * (s[0][0] * inv + s[1][0] * inv);
        outp[N_EDGE + 1] = s[2][0] * inv;
    }
}

// atomic-scatter fallback (streaming config only)
__global__ void k_edge(const void* __restrict__ hb, const int* __restrict__ ei,
                       const int* __restrict__ et, const float* __restrict__ compf,
                       float* __restrict__ agg, int b0, float invS) {
    int tid = threadIdx.x;
    int e = blockIdx.x * 2 + (tid >> 7);
    int o = tid & 127;
    int src = ei[e], dst = ei[N_EDGE + e], r = et[e];
    const unsigned char* hp = (const unsigned char*)hb + (size_t)src * 128;
    float m = compf[r * 4 + b0] * invS * e4m32f(hp[o]);
    atomicAdd(&agg[(size_t)dst * 128 + o], m);
}
__global__ void k_xupd(const float* __restrict__ agg, const int* __restrict__ cnt,
                       const float* __restrict__ canon, ushort_t* __restrict__ xbf) {
    int i = blockIdx.x * blockDim.x + threadIdx.x;
    if (i >= N_NODES * 128) return;
    float d = fmaxf((float)cnt[i >> 7], 1.0f);
    xbf[i] = f2bf(fmaxf(agg[i] / d + canon[C_BIAS1 + (i & 127)], 0.f));
}
__global__ void k_x2s(float* __restrict__ agg, const int* __restrict__ cnt,
                      const float* __restrict__ canon) {
    int i = blockIdx.x * blockDim.x + threadIdx.x;
    if (i >= N_NODES * 128) return;
    float d = fmaxf((float)cnt[i >> 7], 1.0f);
    agg[i] = agg[i] / d + canon[C_BIAS2 + (i & 127)];
}

extern "C" void kernel_launch(void* const* d_in, const int* in_sizes, int n_in,
                              void* d_out, int out_size, void* d_ws, size_t ws_size,
                              hipStream_t stream) {
    const void* emb    = d_in[0];
    const void* ebias  = d_in[1];
    const void* bases1 = d_in[2];
    const void* comp1  = d_in[3];
    const void* bias1  = d_in[4];
    const void* bases2 = d_in[5];
    const void* comp2  = d_in[6];
    const void* bias2  = d_in[7];
    const void* rel    = d_in[8];
    const int*  ei     = (const int*)d_in[9];
    const int*  et     = (const int*)d_in[10];
    const int*  neg    = (const int*)d_in[11];
    float*      outp   = (float*)d_out;

    // ---- adaptive config ----
    const size_t commonB = 2 * 1024 * 1024;                                 // smalls, generous
    const size_t aggB    = (size_t)N_NODES * 128 * 4;                       // 25.6 MB
    const size_t needA   = commonB + aggB + (size_t)N_NODES * 512 * 2;      // ~79 MB  bf16 hb
    const size_t needB   = commonB + aggB + (size_t)N_NODES * 512 * 1;      // ~53 MB  fp8 hb
    int fp8, streamC;
    if      (ws_size >= needA) { fp8 = 0; streamC = 0; }
    else if (ws_size >= needB) { fp8 = 1; streamC = 0; }
    else                       { fp8 = 1; streamC = 1; }
    const float S1 = 1024.f, S2 = 2048.f;
    float s1 = fp8 ? S1 : 1.f, s2 = fp8 ? S2 : 1.f;
    float i1 = fp8 ? (1.f / S1) : 1.f, i2 = fp8 ? (1.f / S2) : 1.f;

    char* ws = (char*)d_ws;
    size_t off = 0;
    auto alloc = [&](size_t bytes) { char* p = ws + off; off += (bytes + 255) & ~(size_t)255; return p; };
    int*          flag   = (int*)alloc(256);
    float*        canon  = (float*)alloc((size_t)C_TOTAL * 4);
    int*          cnt    = (int*)alloc((size_t)N_NODES * 4);
    int*          ptr    = (int*)alloc((size_t)(N_NODES + 1) * 4);
    int*          cursor = (int*)alloc((size_t)N_NODES * 4);
    int*          bsum   = (int*)alloc(SCAN_BLOCKS * 4);
    int*          boff   = (int*)alloc(64 * 4);
    ushort_t*     bt1    = (ushort_t*)alloc((size_t)512 * 128 * 2);
    ushort_t*     bt2    = (ushort_t*)alloc((size_t)512 * 128 * 2);
    float*        part   = (float*)alloc((size_t)DM_BLOCKS * 3 * 4);
    unsigned int* packed = (unsigned int*)alloc((size_t)N_EDGE * 4);
    float*        agg    = (float*)alloc(aggB);
    void*         hb     = (void*)alloc((size_t)N_NODES * 512 * (fp8 ? 1 : 2) / (streamC ? 4 : 1));
    ushort_t*     x      = streamC ? (ushort_t*)alloc((size_t)N_NODES * 128 * 2) : nullptr;

    k_detect<<<1, 256, 0, stream>>>((const ushort_t*)emb, flag);
    k_small<<<1, 256, 0, stream>>>(comp1, comp2, bias1, bias2, rel, ebias, canon, flag);
    hipMemsetAsync(cnt, 0, (size_t)N_NODES * 4, stream);
    k_cnt<<<N_EDGE / 256, 256, 0, stream>>>(ei, cnt);
    k_scan1<<<SCAN_BLOCKS, 1024, 0, stream>>>(cnt, ptr, bsum);
    k_scan2<<<1, 64, 0, stream>>>(bsum, boff);
    k_scan3<<<SCAN_BLOCKS, 1024, 0, stream>>>(ptr, cursor, boff);
    k_fill<<<N_EDGE / 256, 256, 0, stream>>>(ei, et, cursor, packed);
    k_repack<<<NBASE * 128 * 128 / 256, 256, 0, stream>>>(bases1, bt1, flag);
    k_repack<<<NBASE * 128 * 128 / 256, 256, 0, stream>>>(bases2, bt2, flag);

    if (!streamC) {
        dim3 ggrid(N_NODES / 16, 8);
        // layer 1: agg = raw scaled sum (omode 0)
        k_gemm<<<ggrid, 64, 0, stream>>>(emb, cnt, canon, bt1, hb, flag, -1, 4, s1, fp8);
        k_agg<<<N_NODES / 2, 256, 0, stream>>>(hb, ptr, packed, canon + C_COMP1, cnt, canon,
                                               agg, i1, fp8, 0);
        // layer 2: gemm mode 2 normalizes inline; k_agg omode 1 emits x2 directly
        k_gemm<<<ggrid, 64, 0, stream>>>(agg, cnt, canon, bt2, hb, flag, 2, 4, s2, fp8);
        k_agg<<<N_NODES / 2, 256, 0, stream>>>(hb, ptr, packed, canon + C_COMP2, cnt, canon,
                                               agg, i2, fp8, 1);
    } else {
        dim3 ggrid(N_NODES / 16, 2);
        hipMemsetAsync(agg, 0, aggB, stream);
        for (int c = 0; c < 4; ++c) {
            k_gemm<<<ggrid, 64, 0, stream>>>(emb, cnt, canon, bt1 + c * 16384, hb, flag, -1, 1, s1, 1);
            k_edge<<<N_EDGE / 2, 256, 0, stream>>>(hb, ei, et, canon + C_COMP1, agg, c, i1);
        }
        k_xupd<<<N_NODES * 128 / 256, 256, 0, stream>>>(agg, cnt, canon, x);
        hipMemsetAsync(agg, 0, aggB, stream);
        for (int c = 0; c < 4; ++c) {
            k_gemm<<<ggrid, 64, 0, stream>>>(x, cnt, canon, bt2 + c * 16384, hb, flag, 3, 1, s2, 1);
            k_edge<<<N_EDGE / 2, 256, 0, stream>>>(hb, ei, et, canon + C_COMP2, agg, c, i2);
        }
        k_x2s<<<N_NODES * 128 / 256, 256, 0, stream>>>(agg, cnt, canon);
    }
    k_distmult8<<<DM_BLOCKS, 256, 0, stream>>>(agg, canon, ei, et, neg, outp, part);
    k_final<<<1, 256, 0, stream>>>(part, outp);
}

// Round 7
// 397.888 us; speedup vs baseline: 2.3034x; 1.3481x over previous
//
#include <hip/hip_runtime.h>

typedef unsigned short ushort_t;
typedef __attribute__((ext_vector_type(8))) short short8;
typedef __attribute__((ext_vector_type(4))) float f32x4;

#define N_NODES 50000
#define NBASE   4
#define N_EDGE  320000
#define DM_BLOCKS 1024
#define N_GROUPS (N_EDGE / 8)
#define SCAN_BLOCKS 49          // 49*1024 = 50176 >= 50000

// canonical fp32 small-tensor layout (element offsets)
#define C_COMP1 0
#define C_COMP2 100
#define C_BIAS1 200
#define C_BIAS2 328
#define C_REL   456
#define C_EBIAS 1992
#define C_TOTAL 2120

__device__ __forceinline__ float bf2f(ushort_t u) {
    union { unsigned int i; float f; } v; v.i = ((unsigned int)u) << 16; return v.f;
}
__device__ __forceinline__ ushort_t f2bf(float f) {
    union { float f; unsigned int i; } v; v.f = f;
    unsigned int u = v.i;
    u = (u + 0x7FFFu + ((u >> 16) & 1u)) >> 16;   // RNE
    return (ushort_t)u;
}
__device__ __forceinline__ float readf(const void* p, int i, int isbf) {
    return isbf ? bf2f(((const ushort_t*)p)[i]) : ((const float*)p)[i];
}
__device__ __forceinline__ float softplus(float x) {
    if (x > 20.f) return x;
    if (x < -20.f) return expf(x);
    return log1pf(expf(x));
}

// Detect float dtype of entity_embedding (bf16 vs fp32) from bit patterns.
__global__ void k_detect(const ushort_t* __restrict__ emb, int* __restrict__ flag) {
    __shared__ int cnt;
    if (threadIdx.x == 0) cnt = 0;
    __syncthreads();
    int e = (emb[threadIdx.x] >> 7) & 0xFF;
    if (e >= 100 && e <= 126) atomicAdd(&cnt, 1);
    __syncthreads();
    if (threadIdx.x == 0) *flag = (cnt >= 200) ? 1 : 0;  // 1 = bf16 inputs
}

__global__ void k_small(const void* comp1, const void* comp2, const void* b1, const void* b2,
                        const void* rel, const void* eb, float* __restrict__ canon,
                        const int* __restrict__ flag) {
    int isbf = *flag;
    for (int i = threadIdx.x; i < C_TOTAL; i += blockDim.x) {
        float v;
        if      (i < C_COMP2) v = readf(comp1, i - C_COMP1, isbf);
        else if (i < C_BIAS1) v = readf(comp2, i - C_COMP2, isbf);
        else if (i < C_BIAS2) v = readf(b1,    i - C_BIAS1, isbf);
        else if (i < C_REL)   v = readf(b2,    i - C_BIAS2, isbf);
        else if (i < C_EBIAS) v = readf(rel,   i - C_REL,   isbf);
        else                  v = readf(eb,    i - C_EBIAS, isbf);
        canon[i] = v;
    }
}

// bases [B,128in,128out] -> btK[o][b*128+i]  (B^T for K=512 GEMM), bf16
__global__ void k_repackK(const void* __restrict__ bases, ushort_t* __restrict__ btK,
                          const int* __restrict__ flag) {
    int isbf = *flag;
    int idx = blockIdx.x * blockDim.x + threadIdx.x;
    if (idx >= NBASE * 128 * 128) return;
    int b = idx >> 14, i = (idx >> 7) & 127, o = idx & 127;
    btK[(size_t)o * 512 + (b << 7) + i] = f2bf(readf(bases, idx, isbf));
}

// ---------------- CSR build (dst-indexed) ----------------
__global__ void k_cnt(const int* __restrict__ ei, int* __restrict__ cnt) {
    int e = blockIdx.x * blockDim.x + threadIdx.x;
    if (e >= N_EDGE) return;
    atomicAdd(&cnt[ei[N_EDGE + e]], 1);
}

__global__ void k_scan1(const int* __restrict__ cnt, int* __restrict__ ptr,
                        int* __restrict__ bsum) {
    __shared__ int s[1024];
    int t = threadIdx.x;
    int i = blockIdx.x * 1024 + t;
    int v = (i < N_NODES) ? cnt[i] : 0;
    s[t] = v;
    __syncthreads();
    for (int off = 1; off < 1024; off <<= 1) {
        int u = (t >= off) ? s[t - off] : 0;
        __syncthreads();
        s[t] += u;
        __syncthreads();
    }
    if (i < N_NODES) ptr[i] = s[t] - v;
    if (t == 1023) bsum[blockIdx.x] = s[1023];
}

__global__ void k_scan2(const int* __restrict__ bsum, int* __restrict__ boff) {
    int t = threadIdx.x;                        // 64
    int v = (t < SCAN_BLOCKS) ? bsum[t] : 0;
    int orig = v;
    #pragma unroll
    for (int off = 1; off < 64; off <<= 1) {
        int u = __shfl_up(v, off);
        if (t >= off) v += u;
    }
    boff[t] = v - orig;
}

__global__ void k_scan3(int* __restrict__ ptr, int* __restrict__ cursor,
                        const int* __restrict__ boff) {
    int t = threadIdx.x;
    int i = blockIdx.x * 1024 + t;
    if (i < N_NODES) {
        int p = ptr[i] + boff[blockIdx.x];
        ptr[i] = p;
        cursor[i] = p;
    }
    if (blockIdx.x == 0 && t == 0) ptr[N_NODES] = N_EDGE;
}

__global__ void k_fill(const int* __restrict__ ei, const int* __restrict__ et,
                       int* __restrict__ cursor, unsigned int* __restrict__ packed) {
    int e = blockIdx.x * blockDim.x + threadIdx.x;
    if (e >= N_EDGE) return;
    int dst = ei[N_EDGE + e];
    int pos = atomicAdd(&cursor[dst], 1);
    packed[pos] = (unsigned int)(ei[e] & 0xFFFF) | ((unsigned int)et[e] << 16);
}

// x = bf16(relu(emb + ebias))
__global__ void k_x0(const void* __restrict__ emb, const float* __restrict__ canon,
                     ushort_t* __restrict__ x, const int* __restrict__ flag) {
    int isbf = *flag;
    int i = blockIdx.x * blockDim.x + threadIdx.x;
    if (i >= N_NODES * 128) return;
    float v = readf(emb, i, isbf) + canon[C_EBIAS + (i & 127)];
    x[i] = f2bf(fmaxf(v, 0.f));
}

// ---------------- pre-projection aggregate (x-space gather) ----------------
// y[m, b*128+o] = sum_{e in CSR[m]} comp[r_e, b] * x[src_e, o]    (bf16 out)
// 2-edge software pipeline: independent load chains per iteration.
__global__ void k_agg2(const ushort_t* __restrict__ x, const int* __restrict__ ptr,
                       const unsigned int* __restrict__ packed, const float* __restrict__ compf,
                       ushort_t* __restrict__ y) {
    __shared__ float sc[100];
    int tid = threadIdx.x;                  // 256 -> 2 nodes/block
    for (int i = tid; i < 100; i += 256) sc[i] = compf[i];
    __syncthreads();
    int m = blockIdx.x * 2 + (tid >> 7);
    int o = tid & 127;
    int beg = ptr[m], end = ptr[m + 1];
    float a0 = 0.f, a1 = 0.f, a2 = 0.f, a3 = 0.f;
    int i = beg;
    for (; i + 2 <= end; i += 2) {
        unsigned int p0 = packed[i], p1 = packed[i + 1];
        float v0 = bf2f(x[(size_t)(p0 & 0xFFFFu) * 128 + o]);
        float v1 = bf2f(x[(size_t)(p1 & 0xFFFFu) * 128 + o]);
        const float* c0 = sc + (p0 >> 16) * 4;
        const float* c1 = sc + (p1 >> 16) * 4;
        a0 += c0[0] * v0; a1 += c0[1] * v0; a2 += c0[2] * v0; a3 += c0[3] * v0;
        a0 += c1[0] * v1; a1 += c1[1] * v1; a2 += c1[2] * v1; a3 += c1[3] * v1;
    }
    if (i < end) {
        unsigned int p0 = packed[i];
        float v0 = bf2f(x[(size_t)(p0 & 0xFFFFu) * 128 + o]);
        const float* c0 = sc + (p0 >> 16) * 4;
        a0 += c0[0] * v0; a1 += c0[1] * v0; a2 += c0[2] * v0; a3 += c0[3] * v0;
    }
    size_t yb = (size_t)m * 512 + o;
    y[yb]       = f2bf(a0);
    y[yb + 128] = f2bf(a1);
    y[yb + 256] = f2bf(a2);
    y[yb + 384] = f2bf(a3);
}

// ---------------- K=512 GEMM: out = post(y @ W) ----------------
// one wave per block: 16 rows x 128 cols, K=512 (16 MFMA steps x 8 col-subtiles)
// epilogue: v = acc/max(cnt,1) + canon[cbias+col]; relu if dorelu; bf16 store.
__global__ void k_gemm512(const ushort_t* __restrict__ y, const ushort_t* __restrict__ btK,
                          const int* __restrict__ cnt, const float* __restrict__ canon,
                          ushort_t* __restrict__ xout, int cbias, int dorelu) {
    int lane = threadIdx.x;
    int m0 = blockIdx.x * 16;
    int r = lane & 15, q = lane >> 4;
    f32x4 acc[8] = {};
    const ushort_t* arow = y + (size_t)(m0 + r) * 512;
    #pragma unroll
    for (int ks = 0; ks < 16; ++ks) {
        int k0 = ks * 32 + q * 8;
        short8 a = *(const short8*)(arow + k0);
        #pragma unroll
        for (int t = 0; t < 8; ++t) {
            short8 b = *(const short8*)(btK + (size_t)(t * 16 + r) * 512 + k0);
            acc[t] = __builtin_amdgcn_mfma_f32_16x16x32_bf16(a, b, acc[t], 0, 0, 0);
        }
    }
    float d[4];
    int rbase = m0 + (q << 2);
    #pragma unroll
    for (int i = 0; i < 4; ++i) d[i] = fmaxf((float)cnt[rbase + i], 1.0f);
    #pragma unroll
    for (int t = 0; t < 8; ++t) {
        int col = t * 16 + r;                  // D: col=lane&15, row=quad*4+reg (m89-verified)
        float bb = canon[cbias + col];
        #pragma unroll
        for (int i = 0; i < 4; ++i) {
            float v = acc[t][i] / d[i] + bb;
            if (dorelu) v = fmaxf(v, 0.f);
            xout[(size_t)(rbase + i) * 128 + col] = f2bf(v);
        }
    }
}

// ---------------- DistMult on bf16 x2: 8 lanes/edge, 8 edges/wave ----------------
__global__ void k_distmult8b(const ushort_t* __restrict__ x2, const float* __restrict__ canon,
                             const int* __restrict__ ei, const int* __restrict__ et,
                             const int* __restrict__ neg, float* __restrict__ outp,
                             float* __restrict__ partials) {
    const float* rel = canon + C_REL;
    int lane = threadIdx.x & 63;
    int g = lane >> 3;                 // edge slot within wave (0..7)
    int l = lane & 7;                  // element group (16 elems each)
    int w = (blockIdx.x * blockDim.x + threadIdx.x) >> 6;
    int nw = (DM_BLOCKS * 256) >> 6;
    float aL1 = 0.f, aL2 = 0.f, aA = 0.f;
    for (int gid = w; gid < N_GROUPS; gid += nw) {
        int e = gid * 8 + g;
        int h = ei[e], t = ei[N_EDGE + e], r = et[e], qn = neg[e];
        const ushort_t* ph = x2 + (size_t)h * 128 + l * 16;
        const ushort_t* pt = x2 + (size_t)t * 128 + l * 16;
        const ushort_t* pq = x2 + (size_t)qn * 128 + l * 16;
        const float*    pr = rel + r * 128 + l * 16;
        short8 h0 = *(const short8*)ph, h1 = *(const short8*)(ph + 8);
        short8 t0 = *(const short8*)pt, t1 = *(const short8*)(pt + 8);
        short8 q0 = *(const short8*)pq, q1 = *(const short8*)(pq + 8);
        float sp = 0.f, sn = 0.f;
        #pragma unroll
        for (int j = 0; j < 8; ++j) {
            float hv = bf2f(((const ushort_t*)&h0)[j]) * pr[j];
            sp += hv * bf2f(((const ushort_t*)&t0)[j]);
            sn += hv * bf2f(((const ushort_t*)&q0)[j]);
        }
        #pragma unroll
        for (int j = 0; j < 8; ++j) {
            float hv = bf2f(((const ushort_t*)&h1)[j]) * pr[8 + j];
            sp += hv * bf2f(((const ushort_t*)&t1)[j]);
            sn += hv * bf2f(((const ushort_t*)&q1)[j]);
        }
        sp += __shfl_down(sp, 4); sn += __shfl_down(sn, 4);
        sp += __shfl_down(sp, 2); sn += __shfl_down(sn, 2);
        sp += __shfl_down(sp, 1); sn += __shfl_down(sn, 1);
        if (l == 0) {
            outp[e] = sp;
            aL1 += softplus(-sp);
            aL2 += softplus(sn);
            aA  += (sp > sn) ? 1.0f : 0.0f;
        }
    }
    #pragma unroll
    for (int off = 32; off; off >>= 1) {
        aL1 += __shfl_down(aL1, off);
        aL2 += __shfl_down(aL2, off);
        aA  += __shfl_down(aA,  off);
    }
    __shared__ float s[3][4];
    int wl = threadIdx.x >> 6;
    if (lane == 0) { s[0][wl] = aL1; s[1][wl] = aL2; s[2][wl] = aA; }
    __syncthreads();
    if (threadIdx.x == 0) {
        float t0 = 0.f, t1 = 0.f, t2 = 0.f;
        for (int i = 0; i < 4; ++i) { t0 += s[0][i]; t1 += s[1][i]; t2 += s[2][i]; }
        partials[blockIdx.x * 3 + 0] = t0;
        partials[blockIdx.x * 3 + 1] = t1;
        partials[blockIdx.x * 3 + 2] = t2;
    }
}

__global__ void k_final(const float* __restrict__ partials, float* __restrict__ outp) {
    __shared__ float s[3][256];
    int tid = threadIdx.x;
    float t0 = 0.f, t1 = 0.f, t2 = 0.f;
    for (int i = tid; i < DM_BLOCKS; i += 256) {
        t0 += partials[i * 3 + 0];
        t1 += partials[i * 3 + 1];
        t2 += partials[i * 3 + 2];
    }
    s[0][tid] = t0; s[1][tid] = t1; s[2][tid] = t2;
    __syncthreads();
    for (int st = 128; st; st >>= 1) {
        if (tid < st) {
            s[0][tid] += s[0][tid + st];
            s[1][tid] += s[1][tid + st];
            s[2][tid] += s[2][tid + st];
        }
        __syncthreads();
    }
    if (tid == 0) {
        float inv = 1.0f / (float)N_EDGE;
        outp[N_EDGE]     = 0.5f * (s[0][0] * inv + s[1][0] * inv);
        outp[N_EDGE + 1] = s[2][0] * inv;
    }
}

extern "C" void kernel_launch(void* const* d_in, const int* in_sizes, int n_in,
                              void* d_out, int out_size, void* d_ws, size_t ws_size,
                              hipStream_t stream) {
    const void* emb    = d_in[0];
    const void* ebias  = d_in[1];
    const void* bases1 = d_in[2];
    const void* comp1  = d_in[3];
    const void* bias1  = d_in[4];
    const void* bases2 = d_in[5];
    const void* comp2  = d_in[6];
    const void* bias2  = d_in[7];
    const void* rel    = d_in[8];
    const int*  ei     = (const int*)d_in[9];
    const int*  et     = (const int*)d_in[10];
    const int*  neg    = (const int*)d_in[11];
    float*      outp   = (float*)d_out;

    char* ws = (char*)d_ws;
    size_t off = 0;
    auto alloc = [&](size_t bytes) { char* p = ws + off; off += (bytes + 255) & ~(size_t)255; return p; };
    int*          flag   = (int*)alloc(256);
    float*        canon  = (float*)alloc((size_t)C_TOTAL * 4);
    int*          cnt    = (int*)alloc((size_t)N_NODES * 4);
    int*          ptr    = (int*)alloc((size_t)(N_NODES + 1) * 4);
    int*          cursor = (int*)alloc((size_t)N_NODES * 4);
    int*          bsum   = (int*)alloc(SCAN_BLOCKS * 4);
    int*          boff   = (int*)alloc(64 * 4);
    ushort_t*     btK1   = (ushort_t*)alloc((size_t)128 * 512 * 2);
    ushort_t*     btK2   = (ushort_t*)alloc((size_t)128 * 512 * 2);
    float*        part   = (float*)alloc((size_t)DM_BLOCKS * 3 * 4);
    unsigned int* packed = (unsigned int*)alloc((size_t)N_EDGE * 4);
    ushort_t*     x      = (ushort_t*)alloc((size_t)N_NODES * 128 * 2);   // 12.8 MB
    ushort_t*     y      = (ushort_t*)alloc((size_t)N_NODES * 512 * 2);   // 51.2 MB
    // total ~67 MB < proven ws_size >= ~78.8 MB

    k_detect<<<1, 256, 0, stream>>>((const ushort_t*)emb, flag);
    k_small<<<1, 256, 0, stream>>>(comp1, comp2, bias1, bias2, rel, ebias, canon, flag);
    hipMemsetAsync(cnt, 0, (size_t)N_NODES * 4, stream);
    k_cnt<<<N_EDGE / 256, 256, 0, stream>>>(ei, cnt);
    k_scan1<<<SCAN_BLOCKS, 1024, 0, stream>>>(cnt, ptr, bsum);
    k_scan2<<<1, 64, 0, stream>>>(bsum, boff);
    k_scan3<<<SCAN_BLOCKS, 1024, 0, stream>>>(ptr, cursor, boff);
    k_fill<<<N_EDGE / 256, 256, 0, stream>>>(ei, et, cursor, packed);
    k_repackK<<<NBASE * 128 * 128 / 256, 256, 0, stream>>>(bases1, btK1, flag);
    k_repackK<<<NBASE * 128 * 128 / 256, 256, 0, stream>>>(bases2, btK2, flag);
    k_x0<<<N_NODES * 128 / 256, 256, 0, stream>>>(emb, canon, x, flag);

    // layer 1: y = gather(comp1 (x) x);  x <- bf16(relu(y@W1 / deg + bias1))
    k_agg2<<<N_NODES / 2, 256, 0, stream>>>(x, ptr, packed, canon + C_COMP1, y);
    k_gemm512<<<N_NODES / 16, 64, 0, stream>>>(y, btK1, cnt, canon, x, C_BIAS1, 1);

    // layer 2: y = gather(comp2 (x) x);  x <- bf16(y@W2 / deg + bias2)   (= x2)
    k_agg2<<<N_NODES / 2, 256, 0, stream>>>(x, ptr, packed, canon + C_COMP2, y);
    k_gemm512<<<N_NODES / 16, 64, 0, stream>>>(y, btK2, cnt, canon, x, C_BIAS2, 0);

    // decode + loss
    k_distmult8b<<<DM_BLOCKS, 256, 0, stream>>>(x, canon, ei, et, neg, outp, part);
    k_final<<<1, 256, 0, stream>>>(part, outp);
}

// Round 8
// 314.298 us; speedup vs baseline: 2.9161x; 1.2660x over previous
//
#include <hip/hip_runtime.h>

typedef unsigned short ushort_t;
typedef __attribute__((ext_vector_type(8))) short short8;
typedef __attribute__((ext_vector_type(4))) float f32x4;

#define N_NODES 50000
#define NBASE   4
#define N_EDGE  320000
#define DM_BLOCKS 1024
#define N_GROUPS (N_EDGE / 8)
#define SCAN_BLOCKS 49          // 49*1024 = 50176 >= 50000
#define LDSB_STRIDE 136         // 128 + 8 ushorts pad: lane bank offset 4 -> 2-way max

// canonical fp32 small-tensor layout (element offsets)
#define C_COMP1 0
#define C_COMP2 100
#define C_BIAS1 200
#define C_BIAS2 328
#define C_REL   456
#define C_EBIAS 1992
#define C_TOTAL 2120

__device__ __forceinline__ float bf2f(ushort_t u) {
    union { unsigned int i; float f; } v; v.i = ((unsigned int)u) << 16; return v.f;
}
__device__ __forceinline__ ushort_t f2bf(float f) {
    union { float f; unsigned int i; } v; v.f = f;
    unsigned int u = v.i;
    u = (u + 0x7FFFu + ((u >> 16) & 1u)) >> 16;   // RNE
    return (ushort_t)u;
}
__device__ __forceinline__ float readf(const void* p, int i, int isbf) {
    return isbf ? bf2f(((const ushort_t*)p)[i]) : ((const float*)p)[i];
}
__device__ __forceinline__ float softplus(float x) {
    if (x > 20.f) return x;
    if (x < -20.f) return expf(x);
    return log1pf(expf(x));
}

// Detect float dtype of entity_embedding (bf16 vs fp32) from bit patterns.
__global__ void k_detect(const ushort_t* __restrict__ emb, int* __restrict__ flag) {
    __shared__ int cnt;
    if (threadIdx.x == 0) cnt = 0;
    __syncthreads();
    int e = (emb[threadIdx.x] >> 7) & 0xFF;
    if (e >= 100 && e <= 126) atomicAdd(&cnt, 1);
    __syncthreads();
    if (threadIdx.x == 0) *flag = (cnt >= 200) ? 1 : 0;  // 1 = bf16 inputs
}

__global__ void k_small(const void* comp1, const void* comp2, const void* b1, const void* b2,
                        const void* rel, const void* eb, float* __restrict__ canon,
                        const int* __restrict__ flag) {
    int isbf = *flag;
    for (int i = threadIdx.x; i < C_TOTAL; i += blockDim.x) {
        float v;
        if      (i < C_COMP2) v = readf(comp1, i - C_COMP1, isbf);
        else if (i < C_BIAS1) v = readf(comp2, i - C_COMP2, isbf);
        else if (i < C_BIAS2) v = readf(b1,    i - C_BIAS1, isbf);
        else if (i < C_REL)   v = readf(b2,    i - C_BIAS2, isbf);
        else if (i < C_EBIAS) v = readf(rel,   i - C_REL,   isbf);
        else                  v = readf(eb,    i - C_EBIAS, isbf);
        canon[i] = v;
    }
}

// bases [B,128in,128out] -> btK[o][b*128+i]  (B^T for K=512 GEMM), bf16
__global__ void k_repackK(const void* __restrict__ bases, ushort_t* __restrict__ btK,
                          const int* __restrict__ flag) {
    int isbf = *flag;
    int idx = blockIdx.x * blockDim.x + threadIdx.x;
    if (idx >= NBASE * 128 * 128) return;
    int b = idx >> 14, i = (idx >> 7) & 127, o = idx & 127;
    btK[(size_t)o * 512 + (b << 7) + i] = f2bf(readf(bases, idx, isbf));
}

// ---------------- CSR build (dst-indexed) ----------------
__global__ void k_cnt(const int* __restrict__ ei, int* __restrict__ cnt) {
    int e = blockIdx.x * blockDim.x + threadIdx.x;
    if (e >= N_EDGE) return;
    atomicAdd(&cnt[ei[N_EDGE + e]], 1);
}

__global__ void k_scan1(const int* __restrict__ cnt, int* __restrict__ ptr,
                        int* __restrict__ bsum) {
    __shared__ int s[1024];
    int t = threadIdx.x;
    int i = blockIdx.x * 1024 + t;
    int v = (i < N_NODES) ? cnt[i] : 0;
    s[t] = v;
    __syncthreads();
    for (int off = 1; off < 1024; off <<= 1) {
        int u = (t >= off) ? s[t - off] : 0;
        __syncthreads();
        s[t] += u;
        __syncthreads();
    }
    if (i < N_NODES) ptr[i] = s[t] - v;
    if (t == 1023) bsum[blockIdx.x] = s[1023];
}

__global__ void k_scan2(const int* __restrict__ bsum, int* __restrict__ boff) {
    int t = threadIdx.x;                        // 64
    int v = (t < SCAN_BLOCKS) ? bsum[t] : 0;
    int orig = v;
    #pragma unroll
    for (int off = 1; off < 64; off <<= 1) {
        int u = __shfl_up(v, off);
        if (t >= off) v += u;
    }
    boff[t] = v - orig;
}

__global__ void k_scan3(int* __restrict__ ptr, int* __restrict__ cursor,
                        const int* __restrict__ boff) {
    int t = threadIdx.x;
    int i = blockIdx.x * 1024 + t;
    if (i < N_NODES) {
        int p = ptr[i] + boff[blockIdx.x];
        ptr[i] = p;
        cursor[i] = p;
    }
    if (blockIdx.x == 0 && t == 0) ptr[N_NODES] = N_EDGE;
}

__global__ void k_fill(const int* __restrict__ ei, const int* __restrict__ et,
                       int* __restrict__ cursor, unsigned int* __restrict__ packed) {
    int e = blockIdx.x * blockDim.x + threadIdx.x;
    if (e >= N_EDGE) return;
    int dst = ei[N_EDGE + e];
    int pos = atomicAdd(&cursor[dst], 1);
    packed[pos] = (unsigned int)(ei[e] & 0xFFFF) | ((unsigned int)et[e] << 16);
}

// x = bf16(relu(emb + ebias))
__global__ void k_x0(const void* __restrict__ emb, const float* __restrict__ canon,
                     ushort_t* __restrict__ x, const int* __restrict__ flag) {
    int isbf = *flag;
    int i = blockIdx.x * blockDim.x + threadIdx.x;
    if (i >= N_NODES * 128) return;
    float v = readf(emb, i, isbf) + canon[C_EBIAS + (i & 127)];
    x[i] = f2bf(fmaxf(v, 0.f));
}

// ---------------- pre-projection aggregate (x-space gather) ----------------
// y[m, b*128+o] = sum_{e in CSR[m]} comp[r_e, b] * x[src_e, o]    (bf16 out)
// 4-edge unroll: independent load chains.
__global__ void k_agg2(const ushort_t* __restrict__ x, const int* __restrict__ ptr,
                       const unsigned int* __restrict__ packed, const float* __restrict__ compf,
                       ushort_t* __restrict__ y) {
    __shared__ float sc[100];
    int tid = threadIdx.x;                  // 256 -> 2 nodes/block
    for (int i = tid; i < 100; i += 256) sc[i] = compf[i];
    __syncthreads();
    int m = blockIdx.x * 2 + (tid >> 7);
    int o = tid & 127;
    int beg = ptr[m], end = ptr[m + 1];
    float a0 = 0.f, a1 = 0.f, a2 = 0.f, a3 = 0.f;
    int i = beg;
    for (; i + 4 <= end; i += 4) {
        unsigned int p0 = packed[i], p1 = packed[i + 1];
        unsigned int p2 = packed[i + 2], p3 = packed[i + 3];
        float v0 = bf2f(x[(size_t)(p0 & 0xFFFFu) * 128 + o]);
        float v1 = bf2f(x[(size_t)(p1 & 0xFFFFu) * 128 + o]);
        float v2 = bf2f(x[(size_t)(p2 & 0xFFFFu) * 128 + o]);
        float v3 = bf2f(x[(size_t)(p3 & 0xFFFFu) * 128 + o]);
        const float* c0 = sc + (p0 >> 16) * 4;
        const float* c1 = sc + (p1 >> 16) * 4;
        const float* c2 = sc + (p2 >> 16) * 4;
        const float* c3 = sc + (p3 >> 16) * 4;
        a0 += c0[0] * v0; a1 += c0[1] * v0; a2 += c0[2] * v0; a3 += c0[3] * v0;
        a0 += c1[0] * v1; a1 += c1[1] * v1; a2 += c1[2] * v1; a3 += c1[3] * v1;
        a0 += c2[0] * v2; a1 += c2[1] * v2; a2 += c2[2] * v2; a3 += c2[3] * v2;
        a0 += c3[0] * v3; a1 += c3[1] * v3; a2 += c3[2] * v3; a3 += c3[3] * v3;
    }
    for (; i < end; ++i) {
        unsigned int p0 = packed[i];
        float v0 = bf2f(x[(size_t)(p0 & 0xFFFFu) * 128 + o]);
        const float* c0 = sc + (p0 >> 16) * 4;
        a0 += c0[0] * v0; a1 += c0[1] * v0; a2 += c0[2] * v0; a3 += c0[3] * v0;
    }
    size_t yb = (size_t)m * 512 + o;
    y[yb]       = f2bf(a0);
    y[yb + 128] = f2bf(a1);
    y[yb + 256] = f2bf(a2);
    y[yb + 384] = f2bf(a3);
}

// ---------------- K=512 GEMM: xout = post(y @ W) ----------------
// 256 thr = 4 waves; M-tile 128 (32 rows/wave), N=128, K=512 in 4 LDS-staged
// chunks of 128. B fragment reused across 2 row-fragments per wave.
// epilogue: v = acc/max(cnt,1) + canon[cbias+col]; relu if dorelu; bf16 store.
__global__ __launch_bounds__(256) void
k_gemm512(const ushort_t* __restrict__ y, const ushort_t* __restrict__ btK,
          const int* __restrict__ cnt, const float* __restrict__ canon,
          ushort_t* __restrict__ xout, int cbias, int dorelu) {
    __shared__ ushort_t bs[128 * LDSB_STRIDE];    // 34.8 KB
    int tid = threadIdx.x;
    int lane = tid & 63, w = tid >> 6;
    int r = lane & 15, q = lane >> 4;
    int m0 = blockIdx.x * 128;
    f32x4 acc[2][8] = {};
    int row0 = m0 + w * 32 + r;                   // fragment 0 row
    int row1 = row0 + 16;                         // fragment 1 row
    int cr0 = (row0 < N_NODES) ? row0 : (N_NODES - 1);   // clamp reads (tail block)
    int cr1 = (row1 < N_NODES) ? row1 : (N_NODES - 1);
    const ushort_t* ar0 = y + (size_t)cr0 * 512;
    const ushort_t* ar1 = y + (size_t)cr1 * 512;

    for (int c = 0; c < 4; ++c) {
        __syncthreads();                          // protect prior-chunk reads
        // stage B chunk: btK[o][c*128 .. +127] -> bs[o*136 ..]
        {
            int o = tid >> 4;                     // 0..15, +16 per step
            int j = (tid & 15) << 3;              // 16B chunk within row (ushorts)
            #pragma unroll
            for (int s = 0; s < 8; ++s, o += 16) {
                short8 v = *(const short8*)(btK + (size_t)o * 512 + c * 128 + j);
                *(short8*)(bs + o * LDSB_STRIDE + j) = v;
            }
        }
        __syncthreads();
        #pragma unroll
        for (int ksl = 0; ksl < 4; ++ksl) {
            int k0 = ksl * 32 + q * 8;
            short8 a0 = *(const short8*)(ar0 + c * 128 + k0);
            short8 a1 = *(const short8*)(ar1 + c * 128 + k0);
            #pragma unroll
            for (int t = 0; t < 8; ++t) {
                short8 b = *(const short8*)(bs + (t * 16 + r) * LDSB_STRIDE + k0);
                acc[0][t] = __builtin_amdgcn_mfma_f32_16x16x32_bf16(a0, b, acc[0][t], 0, 0, 0);
                acc[1][t] = __builtin_amdgcn_mfma_f32_16x16x32_bf16(a1, b, acc[1][t], 0, 0, 0);
            }
        }
    }
    #pragma unroll
    for (int i = 0; i < 2; ++i) {
        int rbase = m0 + w * 32 + i * 16 + (q << 2);
        float d[4];
        #pragma unroll
        for (int ii = 0; ii < 4; ++ii) {
            int rr = rbase + ii;
            d[ii] = fmaxf((float)cnt[(rr < N_NODES) ? rr : (N_NODES - 1)], 1.0f);
        }
        #pragma unroll
        for (int t = 0; t < 8; ++t) {
            int col = t * 16 + r;                 // D: col=lane&15, row=quad*4+reg
            float bb = canon[cbias + col];
            #pragma unroll
            for (int ii = 0; ii < 4; ++ii) {
                int rr = rbase + ii;
                if (rr < N_NODES) {
                    float v = acc[i][t][ii] / d[ii] + bb;
                    if (dorelu) v = fmaxf(v, 0.f);
                    xout[(size_t)rr * 128 + col] = f2bf(v);
                }
            }
        }
    }
}

// ---------------- DistMult on bf16 x2: 8 lanes/edge, 8 edges/wave ----------------
__global__ void k_distmult8b(const ushort_t* __restrict__ x2, const float* __restrict__ canon,
                             const int* __restrict__ ei, const int* __restrict__ et,
                             const int* __restrict__ neg, float* __restrict__ outp,
                             float* __restrict__ partials) {
    __shared__ float srel[1536];                  // 12 rel x 128, 6 KB
    int tid = threadIdx.x;
    for (int i = tid; i < 1536; i += 256) srel[i] = canon[C_REL + i];
    __syncthreads();
    int lane = tid & 63;
    int g = lane >> 3;                 // edge slot within wave (0..7)
    int l = lane & 7;                  // element group (16 elems each)
    int w = (blockIdx.x * blockDim.x + tid) >> 6;
    int nw = (DM_BLOCKS * 256) >> 6;
    float aL1 = 0.f, aL2 = 0.f, aA = 0.f;
    for (int gid = w; gid < N_GROUPS; gid += nw) {
        int e = gid * 8 + g;
        int h = ei[e], t = ei[N_EDGE + e], r = et[e], qn = neg[e];
        const ushort_t* ph = x2 + (size_t)h * 128 + l * 16;
        const ushort_t* pt = x2 + (size_t)t * 128 + l * 16;
        const ushort_t* pq = x2 + (size_t)qn * 128 + l * 16;
        const float*    pr = srel + r * 128 + l * 16;
        short8 h0 = *(const short8*)ph, h1 = *(const short8*)(ph + 8);
        short8 t0 = *(const short8*)pt, t1 = *(const short8*)(pt + 8);
        short8 q0 = *(const short8*)pq, q1 = *(const short8*)(pq + 8);
        float sp = 0.f, sn = 0.f;
        #pragma unroll
        for (int j = 0; j < 8; ++j) {
            float hv = bf2f(((const ushort_t*)&h0)[j]) * pr[j];
            sp += hv * bf2f(((const ushort_t*)&t0)[j]);
            sn += hv * bf2f(((const ushort_t*)&q0)[j]);
        }
        #pragma unroll
        for (int j = 0; j < 8; ++j) {
            float hv = bf2f(((const ushort_t*)&h1)[j]) * pr[8 + j];
            sp += hv * bf2f(((const ushort_t*)&t1)[j]);
            sn += hv * bf2f(((const ushort_t*)&q1)[j]);
        }
        sp += __shfl_down(sp, 4); sn += __shfl_down(sn, 4);
        sp += __shfl_down(sp, 2); sn += __shfl_down(sn, 2);
        sp += __shfl_down(sp, 1); sn += __shfl_down(sn, 1);
        if (l == 0) {
            outp[e] = sp;
            aL1 += softplus(-sp);
            aL2 += softplus(sn);
            aA  += (sp > sn) ? 1.0f : 0.0f;
        }
    }
    #pragma unroll
    for (int off = 32; off; off >>= 1) {
        aL1 += __shfl_down(aL1, off);
        aL2 += __shfl_down(aL2, off);
        aA  += __shfl_down(aA,  off);
    }
    __shared__ float s[3][4];
    int wl = tid >> 6;
    if (lane == 0) { s[0][wl] = aL1; s[1][wl] = aL2; s[2][wl] = aA; }
    __syncthreads();
    if (tid == 0) {
        float t0 = 0.f, t1 = 0.f, t2 = 0.f;
        for (int i = 0; i < 4; ++i) { t0 += s[0][i]; t1 += s[1][i]; t2 += s[2][i]; }
        partials[blockIdx.x * 3 + 0] = t0;
        partials[blockIdx.x * 3 + 1] = t1;
        partials[blockIdx.x * 3 + 2] = t2;
    }
}

__global__ void k_final(const float* __restrict__ partials, float* __restrict__ outp) {
    __shared__ float s[3][256];
    int tid = threadIdx.x;
    float t0 = 0.f, t1 = 0.f, t2 = 0.f;
    for (int i = tid; i < DM_BLOCKS; i += 256) {
        t0 += partials[i * 3 + 0];
        t1 += partials[i * 3 + 1];
        t2 += partials[i * 3 + 2];
    }
    s[0][tid] = t0; s[1][tid] = t1; s[2][tid] = t2;
    __syncthreads();
    for (int st = 128; st; st >>= 1) {
        if (tid < st) {
            s[0][tid] += s[0][tid + st];
            s[1][tid] += s[1][tid + st];
            s[2][tid] += s[2][tid + st];
        }
        __syncthreads();
    }
    if (tid == 0) {
        float inv = 1.0f / (float)N_EDGE;
        outp[N_EDGE]     = 0.5f * (s[0][0] * inv + s[1][0] * inv);
        outp[N_EDGE + 1] = s[2][0] * inv;
    }
}

extern "C" void kernel_launch(void* const* d_in, const int* in_sizes, int n_in,
                              void* d_out, int out_size, void* d_ws, size_t ws_size,
                              hipStream_t stream) {
    const void* emb    = d_in[0];
    const void* ebias  = d_in[1];
    const void* bases1 = d_in[2];
    const void* comp1  = d_in[3];
    const void* bias1  = d_in[4];
    const void* bases2 = d_in[5];
    const void* comp2  = d_in[6];
    const void* bias2  = d_in[7];
    const void* rel    = d_in[8];
    const int*  ei     = (const int*)d_in[9];
    const int*  et     = (const int*)d_in[10];
    const int*  neg    = (const int*)d_in[11];
    float*      outp   = (float*)d_out;

    char* ws = (char*)d_ws;
    size_t off = 0;
    auto alloc = [&](size_t bytes) { char* p = ws + off; off += (bytes + 255) & ~(size_t)255; return p; };
    int*          flag   = (int*)alloc(256);
    float*        canon  = (float*)alloc((size_t)C_TOTAL * 4);
    int*          cnt    = (int*)alloc((size_t)N_NODES * 4);
    int*          ptr    = (int*)alloc((size_t)(N_NODES + 1) * 4);
    int*          cursor = (int*)alloc((size_t)N_NODES * 4);
    int*          bsum   = (int*)alloc(SCAN_BLOCKS * 4);
    int*          boff   = (int*)alloc(64 * 4);
    ushort_t*     btK1   = (ushort_t*)alloc((size_t)128 * 512 * 2);
    ushort_t*     btK2   = (ushort_t*)alloc((size_t)128 * 512 * 2);
    float*        part   = (float*)alloc((size_t)DM_BLOCKS * 3 * 4);
    unsigned int* packed = (unsigned int*)alloc((size_t)N_EDGE * 4);
    ushort_t*     x      = (ushort_t*)alloc((size_t)N_NODES * 128 * 2);   // 12.8 MB
    ushort_t*     y      = (ushort_t*)alloc((size_t)N_NODES * 512 * 2);   // 51.2 MB
    // total ~67 MB < proven ws_size >= ~78.8 MB

    k_detect<<<1, 256, 0, stream>>>((const ushort_t*)emb, flag);
    k_small<<<1, 256, 0, stream>>>(comp1, comp2, bias1, bias2, rel, ebias, canon, flag);
    hipMemsetAsync(cnt, 0, (size_t)N_NODES * 4, stream);
    k_cnt<<<N_EDGE / 256, 256, 0, stream>>>(ei, cnt);
    k_scan1<<<SCAN_BLOCKS, 1024, 0, stream>>>(cnt, ptr, bsum);
    k_scan2<<<1, 64, 0, stream>>>(bsum, boff);
    k_scan3<<<SCAN_BLOCKS, 1024, 0, stream>>>(ptr, cursor, boff);
    k_fill<<<N_EDGE / 256, 256, 0, stream>>>(ei, et, cursor, packed);
    k_repackK<<<NBASE * 128 * 128 / 256, 256, 0, stream>>>(bases1, btK1, flag);
    k_repackK<<<NBASE * 128 * 128 / 256, 256, 0, stream>>>(bases2, btK2, flag);
    k_x0<<<N_NODES * 128 / 256, 256, 0, stream>>>(emb, canon, x, flag);

    int ggrid = (N_NODES + 127) / 128;   // 391

    // layer 1: y = gather(comp1 (x) x);  x <- bf16(relu(y@W1 / deg + bias1))
    k_agg2<<<N_NODES / 2, 256, 0, stream>>>(x, ptr, packed, canon + C_COMP1, y);
    k_gemm512<<<ggrid, 256, 0, stream>>>(y, btK1, cnt, canon, x, C_BIAS1, 1);

    // layer 2: y = gather(comp2 (x) x);  x <- bf16(y@W2 / deg + bias2)   (= x2)
    k_agg2<<<N_NODES / 2, 256, 0, stream>>>(x, ptr, packed, canon + C_COMP2, y);
    k_gemm512<<<ggrid, 256, 0, stream>>>(y, btK2, cnt, canon, x, C_BIAS2, 0);

    // decode + loss
    k_distmult8b<<<DM_BLOCKS, 256, 0, stream>>>(x, canon, ei, et, neg, outp, part);
    k_final<<<1, 256, 0, stream>>>(part, outp);
}

// Round 9
// 282.159 us; speedup vs baseline: 3.2482x; 1.1139x over previous
//
#include <hip/hip_runtime.h>

typedef unsigned short ushort_t;
typedef __attribute__((ext_vector_type(8))) short short8;
typedef __attribute__((ext_vector_type(4))) float f32x4;

#define N_NODES 50000
#define NBASE   4
#define N_EDGE  320000
#define DM_BLOCKS 2048
#define N_GROUPS (N_EDGE / 8)
#define SCAN_BLOCKS 49          // 49*1024 = 50176 >= 50000
#define LDSB_STRIDE 136         // 128 + 8 ushorts pad

// canonical fp32 small-tensor layout (element offsets)
#define C_COMP1 0
#define C_COMP2 100
#define C_BIAS1 200
#define C_BIAS2 328
#define C_REL   456
#define C_EBIAS 1992
#define C_TOTAL 2120

__device__ __forceinline__ float bf2f(ushort_t u) {
    union { unsigned int i; float f; } v; v.i = ((unsigned int)u) << 16; return v.f;
}
__device__ __forceinline__ ushort_t f2bf(float f) {
    union { float f; unsigned int i; } v; v.f = f;
    unsigned int u = v.i;
    u = (u + 0x7FFFu + ((u >> 16) & 1u)) >> 16;   // RNE
    return (ushort_t)u;
}
__device__ __forceinline__ float readf(const void* p, int i, int isbf) {
    return isbf ? bf2f(((const ushort_t*)p)[i]) : ((const float*)p)[i];
}
__device__ __forceinline__ float softplus(float x) {
    if (x > 20.f) return x;
    if (x < -20.f) return expf(x);
    return log1pf(expf(x));
}

// Fused: detect float dtype of emb (phase 1) + canonicalize small tensors (phase 2).
__global__ void k_prep(const ushort_t* __restrict__ emb, int* __restrict__ flag,
                       const void* comp1, const void* comp2, const void* b1, const void* b2,
                       const void* rel, const void* eb, float* __restrict__ canon) {
    __shared__ int cnt;
    if (threadIdx.x == 0) cnt = 0;
    __syncthreads();
    int e = (emb[threadIdx.x] >> 7) & 0xFF;
    if (e >= 100 && e <= 126) atomicAdd(&cnt, 1);
    __syncthreads();
    if (threadIdx.x == 0) *flag = (cnt >= 200) ? 1 : 0;  // 1 = bf16 inputs
    __syncthreads();
    int isbf = (cnt >= 200) ? 1 : 0;
    for (int i = threadIdx.x; i < C_TOTAL; i += blockDim.x) {
        float v;
        if      (i < C_COMP2) v = readf(comp1, i - C_COMP1, isbf);
        else if (i < C_BIAS1) v = readf(comp2, i - C_COMP2, isbf);
        else if (i < C_BIAS2) v = readf(b1,    i - C_BIAS1, isbf);
        else if (i < C_REL)   v = readf(b2,    i - C_BIAS2, isbf);
        else if (i < C_EBIAS) v = readf(rel,   i - C_REL,   isbf);
        else                  v = readf(eb,    i - C_EBIAS, isbf);
        canon[i] = v;
    }
}

// Fused init: blocks [0,256)   -> repack bases1 -> btK1[o][b*128+i]
//             blocks [256,512) -> repack bases2 -> btK2
//             blocks [512, ..) -> x = bf16(relu(emb + ebias))
__global__ void k_init(const void* __restrict__ bases1, ushort_t* __restrict__ btK1,
                       const void* __restrict__ bases2, ushort_t* __restrict__ btK2,
                       const void* __restrict__ emb, const float* __restrict__ canon,
                       ushort_t* __restrict__ x, const int* __restrict__ flag) {
    int isbf = *flag;
    int bid = blockIdx.x;
    if (bid < 512) {
        const void* bases = (bid < 256) ? bases1 : bases2;
        ushort_t* btK = (bid < 256) ? btK1 : btK2;
        int idx = (bid & 255) * 256 + threadIdx.x;      // < 65536
        int b = idx >> 14, i = (idx >> 7) & 127, o = idx & 127;
        btK[(size_t)o * 512 + (b << 7) + i] = f2bf(readf(bases, idx, isbf));
    } else {
        int i = (bid - 512) * 256 + threadIdx.x;
        if (i < N_NODES * 128) {
            float v = readf(emb, i, isbf) + canon[C_EBIAS + (i & 127)];
            x[i] = f2bf(fmaxf(v, 0.f));
        }
    }
}

// ---------------- CSR build (dst-indexed) ----------------
__global__ void k_cnt(const int* __restrict__ ei, int* __restrict__ cnt) {
    int e = blockIdx.x * blockDim.x + threadIdx.x;
    if (e >= N_EDGE) return;
    atomicAdd(&cnt[ei[N_EDGE + e]], 1);
}

__global__ void k_scan1(const int* __restrict__ cnt, int* __restrict__ ptr,
                        int* __restrict__ bsum) {
    __shared__ int s[1024];
    int t = threadIdx.x;
    int i = blockIdx.x * 1024 + t;
    int v = (i < N_NODES) ? cnt[i] : 0;
    s[t] = v;
    __syncthreads();
    for (int off = 1; off < 1024; off <<= 1) {
        int u = (t >= off) ? s[t - off] : 0;
        __syncthreads();
        s[t] += u;
        __syncthreads();
    }
    if (i < N_NODES) ptr[i] = s[t] - v;
    if (t == 1023) bsum[blockIdx.x] = s[1023];
}

__global__ void k_scan2(const int* __restrict__ bsum, int* __restrict__ boff) {
    int t = threadIdx.x;                        // 64
    int v = (t < SCAN_BLOCKS) ? bsum[t] : 0;
    int orig = v;
    #pragma unroll
    for (int off = 1; off < 64; off <<= 1) {
        int u = __shfl_up(v, off);
        if (t >= off) v += u;
    }
    boff[t] = v - orig;
}

__global__ void k_scan3(int* __restrict__ ptr, int* __restrict__ cursor,
                        const int* __restrict__ boff) {
    int t = threadIdx.x;
    int i = blockIdx.x * 1024 + t;
    if (i < N_NODES) {
        int p = ptr[i] + boff[blockIdx.x];
        ptr[i] = p;
        cursor[i] = p;
    }
    if (blockIdx.x == 0 && t == 0) ptr[N_NODES] = N_EDGE;
}

__global__ void k_fill(const int* __restrict__ ei, const int* __restrict__ et,
                       int* __restrict__ cursor, unsigned int* __restrict__ packed) {
    int e = blockIdx.x * blockDim.x + threadIdx.x;
    if (e >= N_EDGE) return;
    int dst = ei[N_EDGE + e];
    int pos = atomicAdd(&cursor[dst], 1);
    packed[pos] = (unsigned int)(ei[e] & 0xFFFF) | ((unsigned int)et[e] << 16);
}

// ---------------- pre-projection aggregate (x-space gather) ----------------
// y[m, b*128+o] = sum_{e in CSR[m]} comp[r_e, b] * x[src_e, o]    (bf16 out)
// ONE WAVE PER NODE: lane owns columns (2*lane, 2*lane+1) as packed bf16x2.
// 4-edge unroll -> 4 independent 256B row loads in flight per wave.
__global__ void k_agg2(const ushort_t* __restrict__ x, const int* __restrict__ ptr,
                       const unsigned int* __restrict__ packed, const float* __restrict__ compf,
                       ushort_t* __restrict__ y) {
    __shared__ float sc[100];
    int tid = threadIdx.x;                  // 256 = 4 waves -> 4 nodes/block
    for (int i = tid; i < 100; i += 256) sc[i] = compf[i];
    __syncthreads();
    int m = blockIdx.x * 4 + (tid >> 6);
    int lane = tid & 63;
    int o2 = lane << 1;                     // column pair
    int beg = ptr[m], end = ptr[m + 1];
    float l0 = 0.f, l1 = 0.f, l2 = 0.f, l3 = 0.f;   // low col, bases 0..3
    float h0 = 0.f, h1 = 0.f, h2 = 0.f, h3 = 0.f;   // high col
    int i = beg;
    for (; i + 4 <= end; i += 4) {
        unsigned int p0 = packed[i], p1 = packed[i + 1];
        unsigned int p2 = packed[i + 2], p3 = packed[i + 3];
        unsigned int w0 = *(const unsigned int*)(x + (size_t)(p0 & 0xFFFFu) * 128 + o2);
        unsigned int w1 = *(const unsigned int*)(x + (size_t)(p1 & 0xFFFFu) * 128 + o2);
        unsigned int w2 = *(const unsigned int*)(x + (size_t)(p2 & 0xFFFFu) * 128 + o2);
        unsigned int w3 = *(const unsigned int*)(x + (size_t)(p3 & 0xFFFFu) * 128 + o2);
        const float* c0 = sc + (p0 >> 16) * 4;
        const float* c1 = sc + (p1 >> 16) * 4;
        const float* c2 = sc + (p2 >> 16) * 4;
        const float* c3 = sc + (p3 >> 16) * 4;
        float vl, vh;
        vl = bf2f((ushort_t)w0); vh = bf2f((ushort_t)(w0 >> 16));
        l0 += c0[0] * vl; l1 += c0[1] * vl; l2 += c0[2] * vl; l3 += c0[3] * vl;
        h0 += c0[0] * vh; h1 += c0[1] * vh; h2 += c0[2] * vh; h3 += c0[3] * vh;
        vl = bf2f((ushort_t)w1); vh = bf2f((ushort_t)(w1 >> 16));
        l0 += c1[0] * vl; l1 += c1[1] * vl; l2 += c1[2] * vl; l3 += c1[3] * vl;
        h0 += c1[0] * vh; h1 += c1[1] * vh; h2 += c1[2] * vh; h3 += c1[3] * vh;
        vl = bf2f((ushort_t)w2); vh = bf2f((ushort_t)(w2 >> 16));
        l0 += c2[0] * vl; l1 += c2[1] * vl; l2 += c2[2] * vl; l3 += c2[3] * vl;
        h0 += c2[0] * vh; h1 += c2[1] * vh; h2 += c2[2] * vh; h3 += c2[3] * vh;
        vl = bf2f((ushort_t)w3); vh = bf2f((ushort_t)(w3 >> 16));
        l0 += c3[0] * vl; l1 += c3[1] * vl; l2 += c3[2] * vl; l3 += c3[3] * vl;
        h0 += c3[0] * vh; h1 += c3[1] * vh; h2 += c3[2] * vh; h3 += c3[3] * vh;
    }
    for (; i < end; ++i) {
        unsigned int p0 = packed[i];
        unsigned int w0 = *(const unsigned int*)(x + (size_t)(p0 & 0xFFFFu) * 128 + o2);
        const float* c0 = sc + (p0 >> 16) * 4;
        float vl = bf2f((ushort_t)w0), vh = bf2f((ushort_t)(w0 >> 16));
        l0 += c0[0] * vl; l1 += c0[1] * vl; l2 += c0[2] * vl; l3 += c0[3] * vl;
        h0 += c0[0] * vh; h1 += c0[1] * vh; h2 += c0[2] * vh; h3 += c0[3] * vh;
    }
    unsigned int* yp = (unsigned int*)(y + (size_t)m * 512 + o2);
    yp[0]   = (unsigned int)f2bf(l0) | ((unsigned int)f2bf(h0) << 16);
    yp[64]  = (unsigned int)f2bf(l1) | ((unsigned int)f2bf(h1) << 16);
    yp[128] = (unsigned int)f2bf(l2) | ((unsigned int)f2bf(h2) << 16);
    yp[192] = (unsigned int)f2bf(l3) | ((unsigned int)f2bf(h3) << 16);
}

// ---------------- K=512 GEMM: xout = post(y @ W) ----------------
__global__ __launch_bounds__(256) void
k_gemm512(const ushort_t* __restrict__ y, const ushort_t* __restrict__ btK,
          const int* __restrict__ cnt, const float* __restrict__ canon,
          ushort_t* __restrict__ xout, int cbias, int dorelu) {
    __shared__ ushort_t bs[128 * LDSB_STRIDE];    // 34.8 KB
    int tid = threadIdx.x;
    int lane = tid & 63, w = tid >> 6;
    int r = lane & 15, q = lane >> 4;
    int m0 = blockIdx.x * 128;
    f32x4 acc[2][8] = {};
    int row0 = m0 + w * 32 + r;
    int row1 = row0 + 16;
    int cr0 = (row0 < N_NODES) ? row0 : (N_NODES - 1);
    int cr1 = (row1 < N_NODES) ? row1 : (N_NODES - 1);
    const ushort_t* ar0 = y + (size_t)cr0 * 512;
    const ushort_t* ar1 = y + (size_t)cr1 * 512;

    for (int c = 0; c < 4; ++c) {
        __syncthreads();
        {
            int o = tid >> 4;
            int j = (tid & 15) << 3;
            #pragma unroll
            for (int s = 0; s < 8; ++s, o += 16) {
                short8 v = *(const short8*)(btK + (size_t)o * 512 + c * 128 + j);
                *(short8*)(bs + o * LDSB_STRIDE + j) = v;
            }
        }
        __syncthreads();
        #pragma unroll
        for (int ksl = 0; ksl < 4; ++ksl) {
            int k0 = ksl * 32 + q * 8;
            short8 a0 = *(const short8*)(ar0 + c * 128 + k0);
            short8 a1 = *(const short8*)(ar1 + c * 128 + k0);
            #pragma unroll
            for (int t = 0; t < 8; ++t) {
                short8 b = *(const short8*)(bs + (t * 16 + r) * LDSB_STRIDE + k0);
                acc[0][t] = __builtin_amdgcn_mfma_f32_16x16x32_bf16(a0, b, acc[0][t], 0, 0, 0);
                acc[1][t] = __builtin_amdgcn_mfma_f32_16x16x32_bf16(a1, b, acc[1][t], 0, 0, 0);
            }
        }
    }
    #pragma unroll
    for (int i = 0; i < 2; ++i) {
        int rbase = m0 + w * 32 + i * 16 + (q << 2);
        float d[4];
        #pragma unroll
        for (int ii = 0; ii < 4; ++ii) {
            int rr = rbase + ii;
            d[ii] = fmaxf((float)cnt[(rr < N_NODES) ? rr : (N_NODES - 1)], 1.0f);
        }
        #pragma unroll
        for (int t = 0; t < 8; ++t) {
            int col = t * 16 + r;                 // D: col=lane&15, row=quad*4+reg
            float bb = canon[cbias + col];
            #pragma unroll
            for (int ii = 0; ii < 4; ++ii) {
                int rr = rbase + ii;
                if (rr < N_NODES) {
                    float v = acc[i][t][ii] / d[ii] + bb;
                    if (dorelu) v = fmaxf(v, 0.f);
                    xout[(size_t)rr * 128 + col] = f2bf(v);
                }
            }
        }
    }
}

// ---------------- DistMult on bf16 x2: 8 lanes/edge, 8 edges/wave ----------------
__global__ void k_distmult8b(const ushort_t* __restrict__ x2, const float* __restrict__ canon,
                             const int* __restrict__ ei, const int* __restrict__ et,
                             const int* __restrict__ neg, float* __restrict__ outp,
                             float* __restrict__ partials) {
    __shared__ float srel[1536];                  // 12 rel x 128, 6 KB
    int tid = threadIdx.x;
    for (int i = tid; i < 1536; i += 256) srel[i] = canon[C_REL + i];
    __syncthreads();
    int lane = tid & 63;
    int g = lane >> 3;
    int l = lane & 7;
    int w = (blockIdx.x * blockDim.x + tid) >> 6;
    int nw = (DM_BLOCKS * 256) >> 6;
    float aL1 = 0.f, aL2 = 0.f, aA = 0.f;
    for (int gid = w; gid < N_GROUPS; gid += nw) {
        int e = gid * 8 + g;
        int h = ei[e], t = ei[N_EDGE + e], r = et[e], qn = neg[e];
        const ushort_t* ph = x2 + (size_t)h * 128 + l * 16;
        const ushort_t* pt = x2 + (size_t)t * 128 + l * 16;
        const ushort_t* pq = x2 + (size_t)qn * 128 + l * 16;
        const float*    pr = srel + r * 128 + l * 16;
        short8 h0 = *(const short8*)ph, h1 = *(const short8*)(ph + 8);
        short8 t0 = *(const short8*)pt, t1 = *(const short8*)(pt + 8);
        short8 q0 = *(const short8*)pq, q1 = *(const short8*)(pq + 8);
        float sp = 0.f, sn = 0.f;
        #pragma unroll
        for (int j = 0; j < 8; ++j) {
            float hv = bf2f(((const ushort_t*)&h0)[j]) * pr[j];
            sp += hv * bf2f(((const ushort_t*)&t0)[j]);
            sn += hv * bf2f(((const ushort_t*)&q0)[j]);
        }
        #pragma unroll
        for (int j = 0; j < 8; ++j) {
            float hv = bf2f(((const ushort_t*)&h1)[j]) * pr[8 + j];
            sp += hv * bf2f(((const ushort_t*)&t1)[j]);
            sn += hv * bf2f(((const ushort_t*)&q1)[j]);
        }
        sp += __shfl_down(sp, 4); sn += __shfl_down(sn, 4);
        sp += __shfl_down(sp, 2); sn += __shfl_down(sn, 2);
        sp += __shfl_down(sp, 1); sn += __shfl_down(sn, 1);
        if (l == 0) {
            outp[e] = sp;
            aL1 += softplus(-sp);
            aL2 += softplus(sn);
            aA  += (sp > sn) ? 1.0f : 0.0f;
        }
    }
    #pragma unroll
    for (int off = 32; off; off >>= 1) {
        aL1 += __shfl_down(aL1, off);
        aL2 += __shfl_down(aL2, off);
        aA  += __shfl_down(aA,  off);
    }
    __shared__ float s[3][4];
    int wl = tid >> 6;
    if (lane == 0) { s[0][wl] = aL1; s[1][wl] = aL2; s[2][wl] = aA; }
    __syncthreads();
    if (tid == 0) {
        float t0 = 0.f, t1 = 0.f, t2 = 0.f;
        for (int i = 0; i < 4; ++i) { t0 += s[0][i]; t1 += s[1][i]; t2 += s[2][i]; }
        partials[blockIdx.x * 3 + 0] = t0;
        partials[blockIdx.x * 3 + 1] = t1;
        partials[blockIdx.x * 3 + 2] = t2;
    }
}

__global__ void k_final(const float* __restrict__ partials, float* __restrict__ outp) {
    __shared__ float s[3][256];
    int tid = threadIdx.x;
    float t0 = 0.f, t1 = 0.f, t2 = 0.f;
    for (int i = tid; i < DM_BLOCKS; i += 256) {
        t0 += partials[i * 3 + 0];
        t1 += partials[i * 3 + 1];
        t2 += partials[i * 3 + 2];
    }
    s[0][tid] = t0; s[1][tid] = t1; s[2][tid] = t2;
    __syncthreads();
    for (int st = 128; st; st >>= 1) {
        if (tid < st) {
            s[0][tid] += s[0][tid + st];
            s[1][tid] += s[1][tid + st];
            s[2][tid] += s[2][tid + st];
        }
        __syncthreads();
    }
    if (tid == 0) {
        float inv = 1.0f / (float)N_EDGE;
        outp[N_EDGE]     = 0.5f * (s[0][0] * inv + s[1][0] * inv);
        outp[N_EDGE + 1] = s[2][0] * inv;
    }
}

extern "C" void kernel_launch(void* const* d_in, const int* in_sizes, int n_in,
                              void* d_out, int out_size, void* d_ws, size_t ws_size,
                              hipStream_t stream) {
    const void* emb    = d_in[0];
    const void* ebias  = d_in[1];
    const void* bases1 = d_in[2];
    const void* comp1  = d_in[3];
    const void* bias1  = d_in[4];
    const void* bases2 = d_in[5];
    const void* comp2  = d_in[6];
    const void* bias2  = d_in[7];
    const void* rel    = d_in[8];
    const int*  ei     = (const int*)d_in[9];
    const int*  et     = (const int*)d_in[10];
    const int*  neg    = (const int*)d_in[11];
    float*      outp   = (float*)d_out;

    char* ws = (char*)d_ws;
    size_t off = 0;
    auto alloc = [&](size_t bytes) { char* p = ws + off; off += (bytes + 255) & ~(size_t)255; return p; };
    int*          flag   = (int*)alloc(256);
    float*        canon  = (float*)alloc((size_t)C_TOTAL * 4);
    int*          cnt    = (int*)alloc((size_t)N_NODES * 4);
    int*          ptr    = (int*)alloc((size_t)(N_NODES + 1) * 4);
    int*          cursor = (int*)alloc((size_t)N_NODES * 4);
    int*          bsum   = (int*)alloc(SCAN_BLOCKS * 4);
    int*          boff   = (int*)alloc(64 * 4);
    ushort_t*     btK1   = (ushort_t*)alloc((size_t)128 * 512 * 2);
    ushort_t*     btK2   = (ushort_t*)alloc((size_t)128 * 512 * 2);
    float*        part   = (float*)alloc((size_t)DM_BLOCKS * 3 * 4);
    unsigned int* packed = (unsigned int*)alloc((size_t)N_EDGE * 4);
    ushort_t*     x      = (ushort_t*)alloc((size_t)N_NODES * 128 * 2);   // 12.8 MB
    ushort_t*     y      = (ushort_t*)alloc((size_t)N_NODES * 512 * 2);   // 51.2 MB
    // total ~67 MB < proven ws_size >= ~78.8 MB

    k_prep<<<1, 256, 0, stream>>>((const ushort_t*)emb, flag, comp1, comp2, bias1, bias2,
                                  rel, ebias, canon);
    hipMemsetAsync(cnt, 0, (size_t)N_NODES * 4, stream);
    k_cnt<<<N_EDGE / 256, 256, 0, stream>>>(ei, cnt);
    k_scan1<<<SCAN_BLOCKS, 1024, 0, stream>>>(cnt, ptr, bsum);
    k_scan2<<<1, 64, 0, stream>>>(bsum, boff);
    k_scan3<<<SCAN_BLOCKS, 1024, 0, stream>>>(ptr, cursor, boff);
    k_fill<<<N_EDGE / 256, 256, 0, stream>>>(ei, et, cursor, packed);
    k_init<<<512 + (N_NODES * 128 + 255) / 256, 256, 0, stream>>>(
        bases1, btK1, bases2, btK2, emb, canon, x, flag);

    int ggrid = (N_NODES + 127) / 128;   // 391

    // layer 1: y = gather(comp1 (x) x);  x <- bf16(relu(y@W1 / deg + bias1))
    k_agg2<<<N_NODES / 4, 256, 0, stream>>>(x, ptr, packed, canon + C_COMP1, y);
    k_gemm512<<<ggrid, 256, 0, stream>>>(y, btK1, cnt, canon, x, C_BIAS1, 1);

    // layer 2: y = gather(comp2 (x) x);  x <- bf16(y@W2 / deg + bias2)   (= x2)
    k_agg2<<<N_NODES / 4, 256, 0, stream>>>(x, ptr, packed, canon + C_COMP2, y);
    k_gemm512<<<ggrid, 256, 0, stream>>>(y, btK2, cnt, canon, x, C_BIAS2, 0);

    // decode + loss
    k_distmult8b<<<DM_BLOCKS, 256, 0, stream>>>(x, canon, ei, et, neg, outp, part);
    k_final<<<1, 256, 0, stream>>>(part, outp);
}